// Round 18
// baseline (1264.888 us; speedup 1.0000x reference)
//
#include <hip/hip_runtime.h>
#include <math.h>

#define HW 16384   // 128*128

typedef __attribute__((ext_vector_type(8))) short short8;
typedef __attribute__((ext_vector_type(4))) float f32x4;
typedef unsigned int u32;

// fast tanh via v_exp_f32 + v_rcp_f32; saturates cleanly at +-inf
__device__ __forceinline__ float fast_tanh(float x) {
    float e = __expf(-2.0f * x);
    return 2.0f * __builtin_amdgcn_rcpf(1.0f + e) - 1.0f;
}
// gelu_tanh(x) = 0.5x(1+tanh(g)) = x * sigmoid(2g)
__device__ __forceinline__ float gelu_tanh(float x) {
    float x3 = x * x * x;
    float g = 0.7978845608028654f * (x + 0.044715f * x3);
    float e = __expf(-2.0f * g);
    return x * __builtin_amdgcn_rcpf(1.0f + e);
}

__device__ __forceinline__ u32 f2bf(float f) {
    u32 u = __builtin_bit_cast(u32, f);
    return (u + 0x7FFFu + ((u >> 16) & 1u)) >> 16;   // RNE bf16
}
__device__ __forceinline__ u32 pack2(float a, float b) {
    return f2bf(a) | (f2bf(b) << 16);
}
__device__ __forceinline__ float bf2f(short s) {
    return __builtin_bit_cast(float, (u32)(unsigned short)s << 16);
}
// direct global->LDS 16B copy; lds base wave-uniform, lane l fills base+l*16
__device__ __forceinline__ void gload16(const void* g, void* l) {
    __builtin_amdgcn_global_load_lds(
        (const __attribute__((address_space(1))) void*)g,
        (__attribute__((address_space(3))) void*)l, 16, 0, 0);
}

// ---------------- const packs ------------------------------------------------------
__global__ __launch_bounds__(256) void packw_kernel(
    const float* __restrict__ cw, short* __restrict__ wpk)
{
    int idx = blockIdx.x * 256 + threadIdx.x;
    if (idx >= 4 * 64 * 576) return;
    int L = idx / 36864, r = idx % 36864;
    int o = r / 576, k = r % 576;
    int tap = k >> 6, i = k & 63;
    wpk[idx] = (short)f2bf(cw[((size_t)(L * 64 + o) * 64 + i) * 9 + tap]);
}
__global__ __launch_bounds__(256) void packpw_kernel(
    const float* __restrict__ pw, short* __restrict__ pwk)
{
    int idx = blockIdx.x * 256 + threadIdx.x;
    if (idx >= 4 * 64 * 128) return;
    int L = idx >> 13, r = idx & 8191;
    int o = r >> 7, k = r & 127;
    pwk[idx] = (short)f2bf(pw[(size_t)L * 8320 + o * 130 + k]);
}
__global__ __launch_bounds__(256) void packfc_kernel(
    const float* __restrict__ fc0w1, const float* __restrict__ fc0w2,
    const float* __restrict__ fc1w1,
    short* __restrict__ w1k, short* __restrict__ w2k, short* __restrict__ f1wk)
{
    int i = blockIdx.x * 256 + threadIdx.x;
    if (i < 4096) {
        int m = i >> 5, k = i & 31;
        w1k[i] = (short)(k < 16 ? f2bf(fc0w1[m * 16 + k]) : 0);
    } else if (i < 10240) {
        int j = i - 4096; int o = j >> 7, m = j & 127;
        w2k[j] = (short)f2bf(fc0w2[o * 128 + m]);
    } else if (i < 18432) {
        int j = i - 10240; int m = j >> 6, c = j & 63;
        f1wk[j] = (short)f2bf(fc1w1[m * 64 + c]);
    }
}
__global__ __launch_bounds__(256) void packsw_kernel(
    const float* __restrict__ sw1r, const float* __restrict__ sw1i,
    const float* __restrict__ sw2r, const float* __restrict__ sw2i,
    u32* __restrict__ wswk)
{
    __shared__ short lr[64][202];
    __shared__ short li[64][202];
    int bi = blockIdx.x;          // 0..511: L = bi>>7, i = (bi>>1)&63, kh = bi&1
    int L = bi >> 7, i = (bi >> 1) & 63, kh = bi & 1;
    int t = threadIdx.x;
    int km0 = kh * 200;
    for (int region = 0; region < 2; ++region) {
        const float* srcR = region ? sw2r : sw1r;
        const float* srcI = region ? sw2i : sw1i;
        size_t sb = ((size_t)(L * 64 + i) * 64) * 400 + km0;
        for (int c = 0; c < 50; ++c) {
            int flat = c * 256 + t;
            int o = flat / 200, km = flat - o * 200;
            lr[o][km] = (short)f2bf(srcR[sb + (size_t)o * 400 + km]);
            li[o][km] = (short)f2bf(srcI[sb + (size_t)o * 400 + km]);
        }
        __syncthreads();
        u32* dst = wswk + ((size_t)L * 800 + (size_t)region * 400 + km0) * 4096 + (size_t)i * 64;
        for (int c = 0; c < 50; ++c) {
            int flat = c * 256 + t;
            int km = flat >> 6, o = flat & 63;
            dst[(size_t)km * 4096 + o] =
                (u32)(unsigned short)lr[o][km] | ((u32)(unsigned short)li[o][km] << 16);
        }
        __syncthreads();
    }
}
__global__ __launch_bounds__(256) void gen_dft_kernel(
    short* __restrict__ Wfg, short* __restrict__ Winvbg,
    short* __restrict__ Tfy, short* __restrict__ Tiy)
{
    int idx = blockIdx.x * 256 + threadIdx.x;
    if (idx < 6144) {
        int n = idx >> 7, xx = idx & 127;
        float val = 0.f;
        if (n < 40) {
            int kx = n >> 1;
            float s, c;
            sincosf(6.283185307179586f * (float)((kx * xx) & 127) / 128.0f, &s, &c);
            val = (n & 1) ? -s : c;
        }
        Wfg[idx] = (short)f2bf(val);
    } else if (idx < 14336) {
        int j = idx - 6144;
        int xx = j >> 6, k = j & 63;
        float val = 0.f;
        if (k < 40) {
            int kx = k >> 1;
            if (kx == 0) {
                val = (k & 1) ? 0.f : (1.0f / 16384.0f);
            } else {
                float s, c;
                sincosf(6.283185307179586f * (float)((kx * xx) & 127) / 128.0f, &s, &c);
                val = ((k & 1) ? -s : c) * (2.0f / 16384.0f);
            }
        }
        Winvbg[j] = (short)f2bf(val);
    } else if (idx < 24576) {
        int j = idx - 14336;      // Tfy [80][128]
        int q = j >> 7, yy = j & 127;
        int kyi = q >> 1;
        int ky = kyi + ((kyi >= 20) ? 88 : 0);
        float s, c;
        sincosf(6.283185307179586f * (float)((ky * yy) & 127) / 128.0f, &s, &c);
        Tfy[j] = (short)f2bf((q & 1) ? s : c);
    } else if (idx < 36864) {
        int j = idx - 24576;      // Tiy [128][96]
        int yy = j / 96, q = j - yy * 96;
        float val = 0.f;
        if (q < 80) {
            int kyi = q >> 1;
            int ky = kyi + ((kyi >= 20) ? 88 : 0);
            float s, c;
            sincosf(6.283185307179586f * (float)((ky * yy) & 127) / 128.0f, &s, &c);
            val = (q & 1) ? s : c;
        }
        Tiy[j] = (short)f2bf(val);
    }
}

// ---------------- front (MFMA): grid+quad+fc0 lift -> xp planar bf16 + xb16 c-last -
__global__ __launch_bounds__(256) void front_mfma_kernel(
    const float* __restrict__ x,
    const float* __restrict__ qa, const float* __restrict__ qb,
    const short* __restrict__ w1k, const float* __restrict__ b1,
    const short* __restrict__ w2k, const float* __restrict__ b2,
    short* __restrict__ xp, short* __restrict__ xb16)
{
    __shared__ short V[128 * 40];
    __shared__ short A2[128 * 136];
    __shared__ float lqa[48], lqb[48], lb1[128], lb2[48];
    int t = threadIdx.x;
    int y = blockIdx.x, b = blockIdx.y;
    int lane = t & 63, w = t >> 6;

    if (t < 48) { lqa[t] = qa[t]; lqb[t] = qb[t]; lb2[t] = b2[t]; }
    if (t >= 128) lb1[t - 128] = b1[t - 128];
    __syncthreads();

    if (t < 128) {
        int xx = t;
        float v[16];
        const float* xsrc = x + (size_t)b * 10 * HW + y * 128 + xx;
#pragma unroll
        for (int c = 0; c < 10; ++c) v[c] = xsrc[c * HW];
        v[10] = (float)y * (1.0f / 127.0f);
        v[11] = (float)xx * (1.0f / 127.0f);
#pragma unroll
        for (int o = 0; o < 4; ++o) {
            float sa = 0.f, sb = 0.f;
#pragma unroll
            for (int c = 0; c < 12; ++c) { sa += lqa[o * 12 + c] * v[c]; sb += lqb[o * 12 + c] * v[c]; }
            v[12 + o] = sa * sb;
        }
        u32* vr = (u32*)&V[xx * 40];
#pragma unroll
        for (int j = 0; j < 8; ++j) vr[j] = pack2(v[2 * j], v[2 * j + 1]);
#pragma unroll
        for (int j = 8; j < 16; ++j) vr[j] = 0u;
        short* op = xp + (size_t)b * 64 * HW + y * 128 + xx;
#pragma unroll
        for (int c = 0; c < 16; ++c) op[(size_t)c * HW] = (short)f2bf(v[c]);
        u32* hb = (u32*)&xb16[(((size_t)b * 128 + y) * 128 + xx) * 64];
#pragma unroll
        for (int j = 0; j < 8; ++j) hb[j] = vr[j];
    }
    __syncthreads();

    // GEMM-a
    {
        short8 aF[2];
#pragma unroll
        for (int mi = 0; mi < 2; ++mi)
            aF[mi] = *(const short8*)(w1k + ((w * 2 + mi) * 16 + (lane & 15)) * 32 + (lane >> 4) * 8);
        f32x4 acc[2][8];
#pragma unroll
        for (int mi = 0; mi < 2; ++mi)
#pragma unroll
            for (int nf = 0; nf < 8; ++nf) acc[mi][nf] = (f32x4){0.f, 0.f, 0.f, 0.f};
#pragma unroll
        for (int nf = 0; nf < 8; ++nf) {
            int xx = nf * 16 + (lane & 15);
            short8 bF = *(const short8*)&V[xx * 40 + (lane >> 4) * 8];
#pragma unroll
            for (int mi = 0; mi < 2; ++mi)
                acc[mi][nf] = __builtin_amdgcn_mfma_f32_16x16x32_bf16(aF[mi], bF, acc[mi][nf], 0, 0, 0);
        }
#pragma unroll
        for (int mi = 0; mi < 2; ++mi) {
            int m0 = (w * 2 + mi) * 16 + (lane >> 4) * 4;
            float bb0 = lb1[m0], bb1 = lb1[m0 + 1], bb2 = lb1[m0 + 2], bb3 = lb1[m0 + 3];
#pragma unroll
            for (int nf = 0; nf < 8; ++nf) {
                int xx = nf * 16 + (lane & 15);
                float h0 = gelu_tanh(acc[mi][nf][0] + bb0);
                float h1 = gelu_tanh(acc[mi][nf][1] + bb1);
                float h2 = gelu_tanh(acc[mi][nf][2] + bb2);
                float h3 = gelu_tanh(acc[mi][nf][3] + bb3);
                *(int2*)&A2[xx * 136 + m0] = make_int2(pack2(h0, h1), pack2(h2, h3));
            }
        }
    }
    __syncthreads();

    // GEMM-b
    {
        short8 aF[3][4];
#pragma unroll
        for (int mt = 0; mt < 3; ++mt)
#pragma unroll
            for (int ks = 0; ks < 4; ++ks)
                aF[mt][ks] = *(const short8*)(w2k + (mt * 16 + (lane & 15)) * 128 + ks * 32 + (lane >> 4) * 8);
#pragma unroll
        for (int ni = 0; ni < 2; ++ni) {
            int nt = w * 2 + ni;
            int xx = nt * 16 + (lane & 15);
            f32x4 acc[3];
#pragma unroll
            for (int mt = 0; mt < 3; ++mt) acc[mt] = (f32x4){0.f, 0.f, 0.f, 0.f};
#pragma unroll
            for (int ks = 0; ks < 4; ++ks) {
                short8 bF = *(const short8*)&A2[xx * 136 + ks * 32 + (lane >> 4) * 8];
#pragma unroll
                for (int mt = 0; mt < 3; ++mt)
                    acc[mt] = __builtin_amdgcn_mfma_f32_16x16x32_bf16(aF[mt][ks], bF, acc[mt], 0, 0, 0);
            }
#pragma unroll
            for (int mt = 0; mt < 3; ++mt) {
                int o0 = mt * 16 + (lane >> 4) * 4;
                float r0 = acc[mt][0] + lb2[o0], r1 = acc[mt][1] + lb2[o0 + 1];
                float r2 = acc[mt][2] + lb2[o0 + 2], r3 = acc[mt][3] + lb2[o0 + 3];
                short* op = xp + (size_t)b * 64 * HW + (size_t)(16 + o0) * HW + y * 128 + xx;
                op[0] = (short)f2bf(r0); op[HW] = (short)f2bf(r1);
                op[2 * HW] = (short)f2bf(r2); op[3 * HW] = (short)f2bf(r3);
                *(int2*)&xb16[(((size_t)b * 128 + y) * 128 + xx) * 64 + 16 + o0] =
                    make_int2(pack2(r0, r1), pack2(r2, r3));
            }
        }
    }
}

// ---------------- fused dft1+dft2 (MFMA): per bc, xp (bf16 planar) -> fm [bc][800] --
__global__ __launch_bounds__(256) void dftfwd_kernel(
    const short* __restrict__ xp, const short* __restrict__ Wfg,
    const short* __restrict__ Tfy, float2* __restrict__ fm)
{
    __shared__ short img[128 * 128];
    __shared__ short S[48 * 140];
    int t = threadIdx.x;
    int bc = blockIdx.x;
    int lane = t & 63, w = t >> 6;

    // direct global->LDS: linear dest, pre-swizzled source (x8 ^= y&7)
    const short8* src = (const short8*)(xp + (size_t)bc * HW);
#pragma unroll
    for (int i = 0; i < 8; ++i) {
        int first = (w * 8 + i) * 64;
        int d = first + lane;
        int yq = d >> 4;
        int x8 = (d & 15) ^ (yq & 7);
        gload16(src + yq * 16 + x8, &img[(size_t)first * 8]);
    }
    for (int z = t; z < 560; z += 256) ((u32*)S)[2800 + z] = 0u;

    short8 bF[3][4];
#pragma unroll
    for (int nf = 0; nf < 3; ++nf)
#pragma unroll
        for (int ks = 0; ks < 4; ++ks) {
            int n = nf * 16 + (lane & 15);
            bF[nf][ks] = *(const short8*)(Wfg + n * 128 + ks * 32 + (lane >> 4) * 8);
        }
    __syncthreads();

    {
        f32x4 acc[2][3];
#pragma unroll
        for (int a = 0; a < 2; ++a)
#pragma unroll
            for (int b2 = 0; b2 < 3; ++b2) acc[a][b2] = (f32x4){0.f, 0.f, 0.f, 0.f};
#pragma unroll
        for (int ks = 0; ks < 4; ++ks)
#pragma unroll
            for (int mf = 0; mf < 2; ++mf) {
                int y = w * 32 + mf * 16 + (lane & 15);
                int x0 = ks * 32 + (lane >> 4) * 8;
                short8 aF = *(const short8*)&img[y * 128 + ((((x0 >> 3) ^ (y & 7))) << 3)];
#pragma unroll
                for (int nf = 0; nf < 3; ++nf)
                    acc[mf][nf] = __builtin_amdgcn_mfma_f32_16x16x32_bf16(aF, bF[nf][ks], acc[mf][nf], 0, 0, 0);
            }
#pragma unroll
        for (int mf = 0; mf < 2; ++mf)
#pragma unroll
            for (int nf = 0; nf < 3; ++nf) {
                int n = nf * 16 + (lane & 15);
                if (n < 40) {
                    int y0 = w * 32 + mf * 16 + (lane >> 4) * 4;
                    *(int2*)&S[n * 140 + y0] = make_int2(pack2(acc[mf][nf][0], acc[mf][nf][1]),
                                                         pack2(acc[mf][nf][2], acc[mf][nf][3]));
                }
            }
    }
    __syncthreads();

    float2* fmo = fm + (size_t)bc * 800;
#pragma unroll
    for (int pi = 0; pi < 4; ++pi) {
        int p = w + pi * 4;
        if (p < 15) {
            int mt = p / 3, nt = p % 3;
            f32x4 acc = (f32x4){0.f, 0.f, 0.f, 0.f};
#pragma unroll
            for (int ks = 0; ks < 4; ++ks) {
                short8 aF = *(const short8*)(Tfy + (mt * 16 + (lane & 15)) * 128 + ks * 32 + (lane >> 4) * 8);
                short8 bG = *(const short8*)&S[(nt * 16 + (lane & 15)) * 140 + ks * 32 + (lane >> 4) * 8];
                acc = __builtin_amdgcn_mfma_f32_16x16x32_bf16(aF, bG, acc, 0, 0, 0);
            }
            float p0 = __shfl_xor(acc[0], 1), p1 = __shfl_xor(acc[1], 1);
            float p2 = __shfl_xor(acc[2], 1), p3 = __shfl_xor(acc[3], 1);
            int l15 = lane & 15;
            if (!(l15 & 1)) {
                int kx = nt * 8 + (l15 >> 1);
                if (kx < 20) {
                    int kyi0 = mt * 8 + ((lane >> 4) << 1);
                    fmo[kyi0 * 20 + kx] = make_float2(acc[0] + p1, p0 - acc[1]);
                    fmo[(kyi0 + 1) * 20 + kx] = make_float2(acc[2] + p3, p2 - acc[3]);
                }
            }
        }
    }
}

// ---------------- per-mode 64x64 complex multiply (in-place on fm) -----------------
__global__ __launch_bounds__(256) void specmul_kernel(
    float2* __restrict__ fm,
    const u32* __restrict__ wswk, int nb64)
{
    __shared__ float2 lx[32 * 64];
    __shared__ u32 lw[64 * 64];
    int t = threadIdx.x;
    int lane = t & 63, wv = t >> 6;
    int mode = blockIdx.x;
    const u32* ws = wswk + (size_t)mode * 4096;
    for (int n = t; n < nb64; n += 256)
        lx[n] = fm[(size_t)n * 800 + mode];
#pragma unroll
    for (int i = 0; i < 4; ++i) {        // 1024 chunks of 16B, linear
        int firstc = (wv * 4 + i) * 64;
        gload16(ws + (size_t)(firstc + lane) * 4, &lw[(size_t)firstc * 4]);
    }
    __syncthreads();
    for (int n = t; n < nb64; n += 256) {
        int b = n >> 6, o = n & 63;
        float re = 0.f, imv = 0.f;
        const float2* xb = lx + b * 64;
#pragma unroll 8
        for (int i = 0; i < 64; ++i) {
            float2 a = xb[i];
            u32 wp = lw[i * 64 + o];
            float wr = __builtin_bit_cast(float, wp << 16);
            float wi = __builtin_bit_cast(float, wp & 0xffff0000u);
            re += a.x * wr - a.y * wi;
            imv += a.x * wi + a.y * wr;
        }
        fm[(size_t)n * 800 + mode] = make_float2(re, imv);
    }
}

// ---------------- invA (MFMA): fm [bc][800] -> g bf16 [b][y][c][48] ----------------
__global__ __launch_bounds__(256) void invA_mfma_kernel(
    const float2* __restrict__ fm, const short* __restrict__ Tiy,
    short* __restrict__ g)
{
    __shared__ short F[48 * 104];
    int t = threadIdx.x;
    int bc = blockIdx.x;
    int lane = t & 63, w = t >> 6;
    int bb = bc >> 6, cc = bc & 63;
    u32* Fw = (u32*)F;
    const float2* src = fm + (size_t)bc * 800;
    for (int i = t; i < 800; i += 256) {
        float2 v = src[i];
        int kyi = i / 20, kx = i - kyi * 20;
        Fw[(2 * kx) * 52 + kyi]     = pack2(v.x, -v.y);
        Fw[(2 * kx + 1) * 52 + kyi] = pack2(v.y, v.x);
    }
    for (int i = t; i < 416; i += 256) Fw[2080 + i] = 0u;
    for (int i = t; i < 384; i += 256) {
        int n = i >> 3, k = i & 7;
        Fw[n * 52 + 40 + k] = 0u;
    }
    __syncthreads();

    short8 aF[3][3];
#pragma unroll
    for (int mt = 0; mt < 3; ++mt)
#pragma unroll
        for (int ks = 0; ks < 3; ++ks)
            aF[mt][ks] = *(const short8*)&F[(mt * 16 + (lane & 15)) * 104 + ks * 32 + (lane >> 4) * 8];

#pragma unroll
    for (int ni = 0; ni < 2; ++ni) {
        int nt = w * 2 + ni;
        int yy = nt * 16 + (lane & 15);
        short8 bF[3];
#pragma unroll
        for (int ks = 0; ks < 3; ++ks)
            bF[ks] = *(const short8*)(Tiy + yy * 96 + ks * 32 + (lane >> 4) * 8);
#pragma unroll
        for (int mt = 0; mt < 3; ++mt) {
            f32x4 acc = (f32x4){0.f, 0.f, 0.f, 0.f};
#pragma unroll
            for (int ks = 0; ks < 3; ++ks)
                acc = __builtin_amdgcn_mfma_f32_16x16x32_bf16(aF[mt][ks], bF[ks], acc, 0, 0, 0);
            int n0 = mt * 16 + (lane >> 4) * 4;
            *(int2*)&g[(((size_t)bb * 128 + yy) * 64 + cc) * 48 + n0] =
                make_int2(pack2(acc[0], acc[1]), pack2(acc[2], acc[3]));
        }
    }
}

// ---------------- fused conv3 + invB + combine: per (b, y-row) ---------------------
// bf16 spine: residual from LDS row 1 (x_old); S1 overlays row 0, C2 overlays row 2.
__global__ __launch_bounds__(256) void convcomb_kernel(
    const short* __restrict__ xb16o,  // [b][y][x][64] bf16 (prev layer)
    const short* __restrict__ wpk,
    const float* __restrict__ cb,
    const short* __restrict__ g,      // [b][y][c][48] bf16
    const short* __restrict__ Winvbg,
    const short* __restrict__ pwk,
    const float* __restrict__ pw,
    const float* __restrict__ pb,
    short* __restrict__ xb16n,
    short* __restrict__ xp)
{
    __shared__ short xlds[3 * 128 * 64];  // rows y-1,y,y+1; post: S1 @row0, C2 @row2
    __shared__ float2 pr[128];
    int t = threadIdx.x;
    int y = blockIdx.x;
    int b = blockIdx.y;
    int lane = t & 63, wid = t >> 6;
    short8 vz = {0, 0, 0, 0, 0, 0, 0, 0};

    // ---- stage rows y-1,y,y+1 direct global->LDS (linear dest, pre-swizzled src) --
    const short8* xs = (const short8*)(xb16o + ((size_t)b * 128) * 128 * 64);
#pragma unroll
    for (int i = 0; i < 12; ++i) {
        int first = (wid * 12 + i) * 64;     // dest chunk base (16B units)
        int d = first + lane;
        int row = d >> 10;
        int xx = (d >> 3) & 127;
        int i8 = (d & 7) ^ (xx & 7);
        int yy = (y + row + 127) & 127;
        gload16(xs + ((size_t)yy * 128 + xx) * 8 + i8, &xlds[(size_t)first * 8]);
    }
    // ---- conv weights (global) ----
    int o0 = wid * 16;
    const short* wbase = wpk + (size_t)(o0 + (lane & 15)) * 576 + (lane >> 4) * 8;
    short8 aFc[18];
#pragma unroll
    for (int s = 0; s < 18; ++s)
        aFc[s] = *(const short8*)(wbase + s * 32);
    // ---- invB A-frags direct from global g row (k zero-pad beyond 48) ----
    short8 aG0, aG1;
    {
        const short* gb = g + ((size_t)(b * 128 + y)) * 64 * 48
                            + (size_t)(o0 + (lane & 15)) * 48;
        aG0 = *(const short8*)(gb + (lane >> 4) * 8);
        aG1 = ((lane >> 4) < 2) ? *(const short8*)(gb + 32 + (lane >> 4) * 8) : vz;
    }
    // ---- Winvbg B-frags ----
    short8 bFi[8][2];
#pragma unroll
    for (int nf = 0; nf < 8; ++nf)
#pragma unroll
        for (int ks = 0; ks < 2; ++ks) {
            int xx = nf * 16 + (lane & 15);
            bFi[nf][ks] = *(const short8*)(Winvbg + xx * 64 + ks * 32 + (lane >> 4) * 8);
        }

    __syncthreads();

    // ---- conv GEMM: accC[8] in registers ----
    f32x4 accC[8];
#pragma unroll
    for (int f = 0; f < 8; ++f) accC[f] = (f32x4){0.f, 0.f, 0.f, 0.f};
#pragma unroll
    for (int s = 0; s < 18; ++s) {
        const int tap = s >> 1;
        const int ky = tap / 3, kx = tap % 3;
        int ig = (s & 1) * 4 + (lane >> 4);
#pragma unroll
        for (int f = 0; f < 8; ++f) {
            int xx = (f * 16 + (lane & 15) + kx + 127) & 127;
            int off = (ky * 128 + xx) * 64 + ((ig ^ (xx & 7)) << 3);
            short8 bG = *(const short8*)&xlds[off];
            accC[f] = __builtin_amdgcn_mfma_f32_16x16x32_bf16(aFc[s], bG, accC[f], 0, 0, 0);
        }
    }
    // ---- invB GEMM: accI[8] in registers ----
    f32x4 accI[8];
#pragma unroll
    for (int nf = 0; nf < 8; ++nf) {
        f32x4 acc = (f32x4){0.f, 0.f, 0.f, 0.f};
        acc = __builtin_amdgcn_mfma_f32_16x16x32_bf16(aG0, bFi[nf][0], acc, 0, 0, 0);
        acc = __builtin_amdgcn_mfma_f32_16x16x32_bf16(aG1, bFi[nf][1], acc, 0, 0, 0);
        accI[nf] = acc;
    }

    __syncthreads();   // all conv reads done; rows 0 & 2 reusable (row 1 = y kept!)

    // ---- write S1 (xlds row0 @0) + pr, C2 (xlds row2 @16384) = accC + bias ----
    short* S1 = xlds;
    short* C2 = xlds + 16384;
    {
        int cw = o0 + (lane >> 4) * 4;
        int swg = (cw >> 3) & 7;
        int cwo = cw & 7;
        bool dopr = (wid == 0) && ((lane >> 4) == 0);
#pragma unroll
        for (int nf = 0; nf < 8; ++nf) {
            int xx = nf * 16 + (lane & 15);
            int dst = xx * 64 + ((swg ^ (xx & 7)) << 3) + cwo;
            *(int2*)&S1[dst] = make_int2(pack2(accI[nf][0], accI[nf][1]),
                                         pack2(accI[nf][2], accI[nf][3]));
            if (dopr) pr[xx] = make_float2(accI[nf][0] * accI[nf][2],
                                           accI[nf][1] * accI[nf][3]);
        }
        float bias0 = cb[cw], bias1 = cb[cw + 1], bias2 = cb[cw + 2], bias3 = cb[cw + 3];
#pragma unroll
        for (int f = 0; f < 8; ++f) {
            int xx = f * 16 + (lane & 15);
            int dst = xx * 64 + ((swg ^ (xx & 7)) << 3) + cwo;
            *(int2*)&C2[dst] = make_int2(pack2(accC[f][0] + bias0, accC[f][1] + bias1),
                                         pack2(accC[f][2] + bias2, accC[f][3] + bias3));
        }
    }
    // ---- pw B-frags ----
    short8 bFp[4][4];
#pragma unroll
    for (int nf = 0; nf < 4; ++nf)
#pragma unroll
        for (int ks = 0; ks < 4; ++ks) {
            int o = nf * 16 + (lane & 15);
            bFp[nf][ks] = *(const short8*)(pwk + o * 128 + ks * 32 + (lane >> 4) * 8);
        }
    __syncthreads();   // S1/C2/pr visible

    // ---- combine GEMM ----
    f32x4 acc[2][4];
#pragma unroll
    for (int a = 0; a < 2; ++a)
#pragma unroll
        for (int b2 = 0; b2 < 4; ++b2) acc[a][b2] = (f32x4){0.f, 0.f, 0.f, 0.f};

#pragma unroll
    for (int ks = 0; ks < 4; ++ks)
#pragma unroll
        for (int mf = 0; mf < 2; ++mf) {
            int xx = wid * 32 + mf * 16 + (lane & 15);
            int k0 = ks * 32 + (lane >> 4) * 8;
            const short* src = (ks < 2) ? &S1[xx * 64 + ((((k0 >> 3) ^ (xx & 7))) << 3)]
                                        : &C2[xx * 64 + (((((k0 - 64) >> 3) ^ (xx & 7))) << 3)];
            short8 aF = *(const short8*)src;
#pragma unroll
            for (int nf = 0; nf < 4; ++nf)
                acc[mf][nf] = __builtin_amdgcn_mfma_f32_16x16x32_bf16(aF, bFp[nf][ks], acc[mf][nf], 0, 0, 0);
        }

    // ---- epilogue: residual (x_old from LDS row1) + fast tanh -> xb16n + xp ----
#pragma unroll
    for (int mf = 0; mf < 2; ++mf) {
        int xr = wid * 32 + mf * 16 + (lane >> 4) * 4;
        float2 prv0 = pr[xr], prv1 = pr[xr + 1], prv2 = pr[xr + 2], prv3 = pr[xr + 3];
#pragma unroll
        for (int nf = 0; nf < 4; ++nf) {
            int o = nf * 16 + (lane & 15);
            const float* pwrow = pw + o * 130;
            float pw128 = pwrow[128], pw129 = pwrow[129], pbv = pb[o];
            int og = o >> 3, oc = o & 7;
            float xo0 = bf2f(xlds[(128 + xr    ) * 64 + ((og ^ ((xr    ) & 7)) << 3) + oc]);
            float xo1 = bf2f(xlds[(128 + xr + 1) * 64 + ((og ^ ((xr + 1) & 7)) << 3) + oc]);
            float xo2 = bf2f(xlds[(128 + xr + 2) * 64 + ((og ^ ((xr + 2) & 7)) << 3) + oc]);
            float xo3 = bf2f(xlds[(128 + xr + 3) * 64 + ((og ^ ((xr + 3) & 7)) << 3) + oc]);
            float r0 = xo0 + fast_tanh(acc[mf][nf][0] + pbv + pw128 * prv0.x + pw129 * prv0.y);
            float r1 = xo1 + fast_tanh(acc[mf][nf][1] + pbv + pw128 * prv1.x + pw129 * prv1.y);
            float r2 = xo2 + fast_tanh(acc[mf][nf][2] + pbv + pw128 * prv2.x + pw129 * prv2.y);
            float r3 = xo3 + fast_tanh(acc[mf][nf][3] + pbv + pw128 * prv3.x + pw129 * prv3.y);
            size_t hbase = (((size_t)(b * 128 + y)) * 128 + xr) * 64 + o;
            xb16n[hbase]       = (short)f2bf(r0);
            xb16n[hbase + 64]  = (short)f2bf(r1);
            xb16n[hbase + 128] = (short)f2bf(r2);
            xb16n[hbase + 192] = (short)f2bf(r3);
            *(int2*)&xp[((size_t)(b * 64 + o)) * HW + y * 128 + xr] =
                make_int2(pack2(r0, r1), pack2(r2, r3));
        }
    }
}

// ---------------- fc1 (MFMA): xb16 -> gelu MLP -> out ------------------------------
__global__ __launch_bounds__(256) void fc1_mfma_kernel(
    const short* __restrict__ xb16,
    const short* __restrict__ f1wk, const float* __restrict__ b1,
    const float* __restrict__ w2, const float* __restrict__ b2,
    float* __restrict__ out)
{
    __shared__ short X[128 * 64];
    __shared__ float lb1[128], lw2[128];
    int t = threadIdx.x;
    int y = blockIdx.x, b = blockIdx.y;
    int lane = t & 63, w = t >> 6;
    if (t < 128) { lb1[t] = b1[t]; lw2[t] = w2[t]; }
    const short8* src = (const short8*)(xb16 + (((size_t)b * 128 + y) * 128) * 64);
#pragma unroll
    for (int i = 0; i < 4; ++i) {
        int first = (w * 4 + i) * 64;
        int d = first + lane;
        int xx = d >> 3;
        int c8 = (d & 7) ^ (xx & 7);
        gload16(src + xx * 8 + c8, &X[(size_t)first * 8]);
    }
    __syncthreads();

    float part0 = 0.f, part1 = 0.f;
#pragma unroll
    for (int mt = 0; mt < 8; ++mt) {
        short8 aF[2];
#pragma unroll
        for (int ks = 0; ks < 2; ++ks)
            aF[ks] = *(const short8*)(f1wk + (mt * 16 + (lane & 15)) * 64 + ks * 32 + (lane >> 4) * 8);
#pragma unroll
        for (int ni = 0; ni < 2; ++ni) {
            int xx = (w * 2 + ni) * 16 + (lane & 15);
            f32x4 acc = (f32x4){0.f, 0.f, 0.f, 0.f};
#pragma unroll
            for (int ks = 0; ks < 2; ++ks) {
                int g8 = ks * 4 + (lane >> 4);
                short8 bF = *(const short8*)&X[xx * 64 + ((g8 ^ (xx & 7)) << 3)];
                acc = __builtin_amdgcn_mfma_f32_16x16x32_bf16(aF[ks], bF, acc, 0, 0, 0);
            }
            int m0 = mt * 16 + (lane >> 4) * 4;
            float s = lw2[m0]     * gelu_tanh(acc[0] + lb1[m0])
                    + lw2[m0 + 1] * gelu_tanh(acc[1] + lb1[m0 + 1])
                    + lw2[m0 + 2] * gelu_tanh(acc[2] + lb1[m0 + 2])
                    + lw2[m0 + 3] * gelu_tanh(acc[3] + lb1[m0 + 3]);
            if (ni == 0) part0 += s; else part1 += s;
        }
    }
    part0 += __shfl_xor(part0, 16); part0 += __shfl_xor(part0, 32);
    part1 += __shfl_xor(part1, 16); part1 += __shfl_xor(part1, 32);
    if (lane < 16) {
        float bb = b2[0];
        out[(size_t)b * HW + y * 128 + (w * 2) * 16 + lane] = part0 + bb;
        out[(size_t)b * HW + y * 128 + (w * 2 + 1) * 16 + lane] = part1 + bb;
    }
}

extern "C" void kernel_launch(void* const* d_in, const int* in_sizes, int n_in,
                              void* d_out, int out_size, void* d_ws, size_t ws_size,
                              hipStream_t stream) {
    const float* x      = (const float*)d_in[0];
    const float* qa     = (const float*)d_in[1];
    const float* qb     = (const float*)d_in[2];
    const float* fc0w1  = (const float*)d_in[3];
    const float* fc0b1  = (const float*)d_in[4];
    const float* fc0w2  = (const float*)d_in[5];
    const float* fc0b2  = (const float*)d_in[6];
    const float* sw1r   = (const float*)d_in[7];
    const float* sw1i   = (const float*)d_in[8];
    const float* sw2r   = (const float*)d_in[9];
    const float* sw2i   = (const float*)d_in[10];
    const float* cw     = (const float*)d_in[11];
    const float* cb     = (const float*)d_in[12];
    const float* pw     = (const float*)d_in[13];
    const float* pb     = (const float*)d_in[14];
    const float* fc1w1  = (const float*)d_in[15];
    const float* fc1b1  = (const float*)d_in[16];
    const float* fc1w2  = (const float*)d_in[17];
    const float* fc1b2  = (const float*)d_in[18];

    // const packs (floats)
    const size_t WPK_F = 73728, PWK_F = 16384, WFG_F = 3072, WIB_F = 4096;
    const size_t TFY_F = 5120, TIY_F = 6144, FCK_F = 9216;
    const size_t WSW_F = 13107200;
    const size_t CONST_F = WPK_F + PWK_F + WFG_F + WIB_F + TFY_F + TIY_F + FCK_F + WSW_F;
    // per-batch floats: xb16A 524288 + xb16B 524288 + xp 524288 + g 196608 + fm 102400
    const size_t PER_B_F = 3u * 524288u + 196608u + 102400u;
    int NB = 32;
    while (NB > 1 && ((size_t)NB * PER_B_F + CONST_F) * 4 > ws_size) NB >>= 1;
    if (((size_t)NB * PER_B_F + CONST_F) * 4 > ws_size) return;

    float* fb = (float*)d_ws;
    short* wpk    = (short*)fb;                 fb += WPK_F;
    short* pwk    = (short*)fb;                 fb += PWK_F;
    short* Wfg    = (short*)fb;                 fb += WFG_F;
    short* Winvbg = (short*)fb;                 fb += WIB_F;
    short* Tfy    = (short*)fb;                 fb += TFY_F;
    short* Tiy    = (short*)fb;                 fb += TIY_F;
    short* w1k    = (short*)fb;
    short* w2k    = w1k + 4096;
    short* f1wk   = w1k + 10240;                fb += FCK_F;
    u32*   wswk   = (u32*)fb;                   fb += WSW_F;

    short*  xb16A = (short*)fb;
    short*  xb16B = xb16A + (size_t)NB * 1048576u;
    short*  xp    = xb16B + (size_t)NB * 1048576u;
    short*  g     = xp + (size_t)NB * 1048576u;
    float2* fm    = (float2*)(g + (size_t)NB * 393216u);

    packw_kernel<<<576, 256, 0, stream>>>(cw, wpk);
    packpw_kernel<<<128, 256, 0, stream>>>(pw, pwk);
    packfc_kernel<<<72, 256, 0, stream>>>(fc0w1, fc0w2, fc1w1, w1k, w2k, f1wk);
    gen_dft_kernel<<<144, 256, 0, stream>>>(Wfg, Winvbg, Tfy, Tiy);
    packsw_kernel<<<512, 256, 0, stream>>>(sw1r, sw1i, sw2r, sw2i, wswk);

    for (int b0 = 0; b0 < 32; b0 += NB) {
        front_mfma_kernel<<<dim3(128, NB), 256, 0, stream>>>(
            x + (size_t)b0 * 10 * HW, qa, qb, w1k, fc0b1, w2k, fc0b2, xp, xb16A);

        short* xo = xb16A;
        short* xn = xb16B;
        for (int L = 0; L < 4; ++L) {
            dftfwd_kernel<<<NB * 64, 256, 0, stream>>>(xp, Wfg, Tfy, fm);
            specmul_kernel<<<800, 256, 0, stream>>>(fm, wswk + (size_t)L * 800 * 4096,
                                                    NB * 64);
            invA_mfma_kernel<<<NB * 64, 256, 0, stream>>>(fm, Tiy, g);
            convcomb_kernel<<<dim3(128, NB), 256, 0, stream>>>(
                xo, wpk + (size_t)L * 36864, cb + (size_t)L * 64,
                g, Winvbg, pwk + (size_t)L * 8192, pw + (size_t)L * 8320,
                pb + (size_t)L * 64, xn, xp);
            short* tmp = xo; xo = xn; xn = tmp;
        }

        fc1_mfma_kernel<<<dim3(128, NB), 256, 0, stream>>>(
            xo, f1wk, fc1b1, fc1w2, fc1b2, (float*)d_out + (size_t)b0 * HW);
    }
}

// Round 19
// 1248.707 us; speedup vs baseline: 1.0130x; 1.0130x over previous
//
#include <hip/hip_runtime.h>
#include <math.h>

#define HW 16384   // 128*128

typedef __attribute__((ext_vector_type(8))) short short8;
typedef __attribute__((ext_vector_type(4))) float f32x4;
typedef unsigned int u32;

// fast tanh via v_exp_f32 + v_rcp_f32; saturates cleanly at +-inf
__device__ __forceinline__ float fast_tanh(float x) {
    float e = __expf(-2.0f * x);
    return 2.0f * __builtin_amdgcn_rcpf(1.0f + e) - 1.0f;
}
// gelu_tanh(x) = 0.5x(1+tanh(g)) = x * sigmoid(2g)
__device__ __forceinline__ float gelu_tanh(float x) {
    float x3 = x * x * x;
    float g = 0.7978845608028654f * (x + 0.044715f * x3);
    float e = __expf(-2.0f * g);
    return x * __builtin_amdgcn_rcpf(1.0f + e);
}

__device__ __forceinline__ u32 f2bf(float f) {
    u32 u = __builtin_bit_cast(u32, f);
    return (u + 0x7FFFu + ((u >> 16) & 1u)) >> 16;   // RNE bf16
}
__device__ __forceinline__ u32 pack2(float a, float b) {
    return f2bf(a) | (f2bf(b) << 16);
}
__device__ __forceinline__ float bf2f(short s) {
    return __builtin_bit_cast(float, (u32)(unsigned short)s << 16);
}

// ---------------- const packs ------------------------------------------------------
__global__ __launch_bounds__(256) void packw_kernel(
    const float* __restrict__ cw, short* __restrict__ wpk)
{
    int idx = blockIdx.x * 256 + threadIdx.x;
    if (idx >= 4 * 64 * 576) return;
    int L = idx / 36864, r = idx % 36864;
    int o = r / 576, k = r % 576;
    int tap = k >> 6, i = k & 63;
    wpk[idx] = (short)f2bf(cw[((size_t)(L * 64 + o) * 64 + i) * 9 + tap]);
}
__global__ __launch_bounds__(256) void packpw_kernel(
    const float* __restrict__ pw, short* __restrict__ pwk)
{
    int idx = blockIdx.x * 256 + threadIdx.x;
    if (idx >= 4 * 64 * 128) return;
    int L = idx >> 13, r = idx & 8191;
    int o = r >> 7, k = r & 127;
    pwk[idx] = (short)f2bf(pw[(size_t)L * 8320 + o * 130 + k]);
}
__global__ __launch_bounds__(256) void packfc_kernel(
    const float* __restrict__ fc0w1, const float* __restrict__ fc0w2,
    const float* __restrict__ fc1w1,
    short* __restrict__ w1k, short* __restrict__ w2k, short* __restrict__ f1wk)
{
    int i = blockIdx.x * 256 + threadIdx.x;
    if (i < 4096) {
        int m = i >> 5, k = i & 31;
        w1k[i] = (short)(k < 16 ? f2bf(fc0w1[m * 16 + k]) : 0);
    } else if (i < 10240) {
        int j = i - 4096; int o = j >> 7, m = j & 127;
        w2k[j] = (short)f2bf(fc0w2[o * 128 + m]);
    } else if (i < 18432) {
        int j = i - 10240; int m = j >> 6, c = j & 63;
        f1wk[j] = (short)f2bf(fc1w1[m * 64 + c]);
    }
}
__global__ __launch_bounds__(256) void packsw_kernel(
    const float* __restrict__ sw1r, const float* __restrict__ sw1i,
    const float* __restrict__ sw2r, const float* __restrict__ sw2i,
    u32* __restrict__ wswk)
{
    __shared__ short lr[64][202];
    __shared__ short li[64][202];
    int bi = blockIdx.x;          // 0..511: L = bi>>7, i = (bi>>1)&63, kh = bi&1
    int L = bi >> 7, i = (bi >> 1) & 63, kh = bi & 1;
    int t = threadIdx.x;
    int km0 = kh * 200;
    for (int region = 0; region < 2; ++region) {
        const float* srcR = region ? sw2r : sw1r;
        const float* srcI = region ? sw2i : sw1i;
        size_t sb = ((size_t)(L * 64 + i) * 64) * 400 + km0;
        for (int c = 0; c < 50; ++c) {
            int flat = c * 256 + t;
            int o = flat / 200, km = flat - o * 200;
            lr[o][km] = (short)f2bf(srcR[sb + (size_t)o * 400 + km]);
            li[o][km] = (short)f2bf(srcI[sb + (size_t)o * 400 + km]);
        }
        __syncthreads();
        u32* dst = wswk + ((size_t)L * 800 + (size_t)region * 400 + km0) * 4096 + (size_t)i * 64;
        for (int c = 0; c < 50; ++c) {
            int flat = c * 256 + t;
            int km = flat >> 6, o = flat & 63;
            dst[(size_t)km * 4096 + o] =
                (u32)(unsigned short)lr[o][km] | ((u32)(unsigned short)li[o][km] << 16);
        }
        __syncthreads();
    }
}
__global__ __launch_bounds__(256) void gen_dft_kernel(
    short* __restrict__ Wfg, short* __restrict__ Winvbg,
    short* __restrict__ Tfy, short* __restrict__ Tiy)
{
    int idx = blockIdx.x * 256 + threadIdx.x;
    if (idx < 6144) {
        int n = idx >> 7, xx = idx & 127;
        float val = 0.f;
        if (n < 40) {
            int kx = n >> 1;
            float s, c;
            sincosf(6.283185307179586f * (float)((kx * xx) & 127) / 128.0f, &s, &c);
            val = (n & 1) ? -s : c;
        }
        Wfg[idx] = (short)f2bf(val);
    } else if (idx < 14336) {
        int j = idx - 6144;
        int xx = j >> 6, k = j & 63;
        float val = 0.f;
        if (k < 40) {
            int kx = k >> 1;
            if (kx == 0) {
                val = (k & 1) ? 0.f : (1.0f / 16384.0f);
            } else {
                float s, c;
                sincosf(6.283185307179586f * (float)((kx * xx) & 127) / 128.0f, &s, &c);
                val = ((k & 1) ? -s : c) * (2.0f / 16384.0f);
            }
        }
        Winvbg[j] = (short)f2bf(val);
    } else if (idx < 24576) {
        int j = idx - 14336;      // Tfy [80][128]
        int q = j >> 7, yy = j & 127;
        int kyi = q >> 1;
        int ky = kyi + ((kyi >= 20) ? 88 : 0);
        float s, c;
        sincosf(6.283185307179586f * (float)((ky * yy) & 127) / 128.0f, &s, &c);
        Tfy[j] = (short)f2bf((q & 1) ? s : c);
    } else if (idx < 36864) {
        int j = idx - 24576;      // Tiy [128][96]
        int yy = j / 96, q = j - yy * 96;
        float val = 0.f;
        if (q < 80) {
            int kyi = q >> 1;
            int ky = kyi + ((kyi >= 20) ? 88 : 0);
            float s, c;
            sincosf(6.283185307179586f * (float)((ky * yy) & 127) / 128.0f, &s, &c);
            val = (q & 1) ? s : c;
        }
        Tiy[j] = (short)f2bf(val);
    }
}

// ---------------- front (MFMA): grid+quad+fc0 lift -> xp planar bf16 + xb16 c-last -
__global__ __launch_bounds__(256) void front_mfma_kernel(
    const float* __restrict__ x,
    const float* __restrict__ qa, const float* __restrict__ qb,
    const short* __restrict__ w1k, const float* __restrict__ b1,
    const short* __restrict__ w2k, const float* __restrict__ b2,
    short* __restrict__ xp, short* __restrict__ xb16)
{
    __shared__ short V[128 * 40];
    __shared__ short A2[128 * 136];
    __shared__ float lqa[48], lqb[48], lb1[128], lb2[48];
    int t = threadIdx.x;
    int y = blockIdx.x, b = blockIdx.y;
    int lane = t & 63, w = t >> 6;

    if (t < 48) { lqa[t] = qa[t]; lqb[t] = qb[t]; lb2[t] = b2[t]; }
    if (t >= 128) lb1[t - 128] = b1[t - 128];
    __syncthreads();

    if (t < 128) {
        int xx = t;
        float v[16];
        const float* xsrc = x + (size_t)b * 10 * HW + y * 128 + xx;
#pragma unroll
        for (int c = 0; c < 10; ++c) v[c] = xsrc[c * HW];
        v[10] = (float)y * (1.0f / 127.0f);
        v[11] = (float)xx * (1.0f / 127.0f);
#pragma unroll
        for (int o = 0; o < 4; ++o) {
            float sa = 0.f, sb = 0.f;
#pragma unroll
            for (int c = 0; c < 12; ++c) { sa += lqa[o * 12 + c] * v[c]; sb += lqb[o * 12 + c] * v[c]; }
            v[12 + o] = sa * sb;
        }
        u32* vr = (u32*)&V[xx * 40];
#pragma unroll
        for (int j = 0; j < 8; ++j) vr[j] = pack2(v[2 * j], v[2 * j + 1]);
#pragma unroll
        for (int j = 8; j < 16; ++j) vr[j] = 0u;
        short* op = xp + (size_t)b * 64 * HW + y * 128 + xx;
#pragma unroll
        for (int c = 0; c < 16; ++c) op[(size_t)c * HW] = (short)f2bf(v[c]);
        u32* hb = (u32*)&xb16[(((size_t)b * 128 + y) * 128 + xx) * 64];
#pragma unroll
        for (int j = 0; j < 8; ++j) hb[j] = vr[j];
    }
    __syncthreads();

    // GEMM-a
    {
        short8 aF[2];
#pragma unroll
        for (int mi = 0; mi < 2; ++mi)
            aF[mi] = *(const short8*)(w1k + ((w * 2 + mi) * 16 + (lane & 15)) * 32 + (lane >> 4) * 8);
        f32x4 acc[2][8];
#pragma unroll
        for (int mi = 0; mi < 2; ++mi)
#pragma unroll
            for (int nf = 0; nf < 8; ++nf) acc[mi][nf] = (f32x4){0.f, 0.f, 0.f, 0.f};
#pragma unroll
        for (int nf = 0; nf < 8; ++nf) {
            int xx = nf * 16 + (lane & 15);
            short8 bF = *(const short8*)&V[xx * 40 + (lane >> 4) * 8];
#pragma unroll
            for (int mi = 0; mi < 2; ++mi)
                acc[mi][nf] = __builtin_amdgcn_mfma_f32_16x16x32_bf16(aF[mi], bF, acc[mi][nf], 0, 0, 0);
        }
#pragma unroll
        for (int mi = 0; mi < 2; ++mi) {
            int m0 = (w * 2 + mi) * 16 + (lane >> 4) * 4;
            float bb0 = lb1[m0], bb1 = lb1[m0 + 1], bb2 = lb1[m0 + 2], bb3 = lb1[m0 + 3];
#pragma unroll
            for (int nf = 0; nf < 8; ++nf) {
                int xx = nf * 16 + (lane & 15);
                float h0 = gelu_tanh(acc[mi][nf][0] + bb0);
                float h1 = gelu_tanh(acc[mi][nf][1] + bb1);
                float h2 = gelu_tanh(acc[mi][nf][2] + bb2);
                float h3 = gelu_tanh(acc[mi][nf][3] + bb3);
                *(int2*)&A2[xx * 136 + m0] = make_int2(pack2(h0, h1), pack2(h2, h3));
            }
        }
    }
    __syncthreads();

    // GEMM-b
    {
        short8 aF[3][4];
#pragma unroll
        for (int mt = 0; mt < 3; ++mt)
#pragma unroll
            for (int ks = 0; ks < 4; ++ks)
                aF[mt][ks] = *(const short8*)(w2k + (mt * 16 + (lane & 15)) * 128 + ks * 32 + (lane >> 4) * 8);
#pragma unroll
        for (int ni = 0; ni < 2; ++ni) {
            int nt = w * 2 + ni;
            int xx = nt * 16 + (lane & 15);
            f32x4 acc[3];
#pragma unroll
            for (int mt = 0; mt < 3; ++mt) acc[mt] = (f32x4){0.f, 0.f, 0.f, 0.f};
#pragma unroll
            for (int ks = 0; ks < 4; ++ks) {
                short8 bF = *(const short8*)&A2[xx * 136 + ks * 32 + (lane >> 4) * 8];
#pragma unroll
                for (int mt = 0; mt < 3; ++mt)
                    acc[mt] = __builtin_amdgcn_mfma_f32_16x16x32_bf16(aF[mt][ks], bF, acc[mt], 0, 0, 0);
            }
#pragma unroll
            for (int mt = 0; mt < 3; ++mt) {
                int o0 = mt * 16 + (lane >> 4) * 4;
                float r0 = acc[mt][0] + lb2[o0], r1 = acc[mt][1] + lb2[o0 + 1];
                float r2 = acc[mt][2] + lb2[o0 + 2], r3 = acc[mt][3] + lb2[o0 + 3];
                short* op = xp + (size_t)b * 64 * HW + (size_t)(16 + o0) * HW + y * 128 + xx;
                op[0] = (short)f2bf(r0); op[HW] = (short)f2bf(r1);
                op[2 * HW] = (short)f2bf(r2); op[3 * HW] = (short)f2bf(r3);
                *(int2*)&xb16[(((size_t)b * 128 + y) * 128 + xx) * 64 + 16 + o0] =
                    make_int2(pack2(r0, r1), pack2(r2, r3));
            }
        }
    }
}

// ---------------- fused dft1+dft2 (MFMA): per bc, xp (bf16 planar) -> fm [bc][800] --
__global__ __launch_bounds__(256) void dftfwd_kernel(
    const short* __restrict__ xp, const short* __restrict__ Wfg,
    const short* __restrict__ Tfy, float2* __restrict__ fm)
{
    __shared__ short img[128 * 128];
    __shared__ short S[48 * 140];
    int t = threadIdx.x;
    int bc = blockIdx.x;
    int lane = t & 63, w = t >> 6;

    const short8* src = (const short8*)(xp + (size_t)bc * HW);
#pragma unroll
    for (int i = 0; i < 8; ++i) {
        int chunk = i * 256 + t;
        int y = chunk >> 4, x8 = chunk & 15;
        short8 v = src[y * 16 + x8];
        *(short8*)&img[y * 128 + ((x8 ^ (y & 7)) << 3)] = v;
    }
    for (int z = t; z < 560; z += 256) ((u32*)S)[2800 + z] = 0u;

    short8 bF[3][4];
#pragma unroll
    for (int nf = 0; nf < 3; ++nf)
#pragma unroll
        for (int ks = 0; ks < 4; ++ks) {
            int n = nf * 16 + (lane & 15);
            bF[nf][ks] = *(const short8*)(Wfg + n * 128 + ks * 32 + (lane >> 4) * 8);
        }
    __syncthreads();

    {
        f32x4 acc[2][3];
#pragma unroll
        for (int a = 0; a < 2; ++a)
#pragma unroll
            for (int b2 = 0; b2 < 3; ++b2) acc[a][b2] = (f32x4){0.f, 0.f, 0.f, 0.f};
#pragma unroll
        for (int ks = 0; ks < 4; ++ks)
#pragma unroll
            for (int mf = 0; mf < 2; ++mf) {
                int y = w * 32 + mf * 16 + (lane & 15);
                int x0 = ks * 32 + (lane >> 4) * 8;
                short8 aF = *(const short8*)&img[y * 128 + ((((x0 >> 3) ^ (y & 7))) << 3)];
#pragma unroll
                for (int nf = 0; nf < 3; ++nf)
                    acc[mf][nf] = __builtin_amdgcn_mfma_f32_16x16x32_bf16(aF, bF[nf][ks], acc[mf][nf], 0, 0, 0);
            }
#pragma unroll
        for (int mf = 0; mf < 2; ++mf)
#pragma unroll
            for (int nf = 0; nf < 3; ++nf) {
                int n = nf * 16 + (lane & 15);
                if (n < 40) {
                    int y0 = w * 32 + mf * 16 + (lane >> 4) * 4;
                    *(int2*)&S[n * 140 + y0] = make_int2(pack2(acc[mf][nf][0], acc[mf][nf][1]),
                                                         pack2(acc[mf][nf][2], acc[mf][nf][3]));
                }
            }
    }
    __syncthreads();

    float2* fmo = fm + (size_t)bc * 800;
#pragma unroll
    for (int pi = 0; pi < 4; ++pi) {
        int p = w + pi * 4;
        if (p < 15) {
            int mt = p / 3, nt = p % 3;
            f32x4 acc = (f32x4){0.f, 0.f, 0.f, 0.f};
#pragma unroll
            for (int ks = 0; ks < 4; ++ks) {
                short8 aF = *(const short8*)(Tfy + (mt * 16 + (lane & 15)) * 128 + ks * 32 + (lane >> 4) * 8);
                short8 bG = *(const short8*)&S[(nt * 16 + (lane & 15)) * 140 + ks * 32 + (lane >> 4) * 8];
                acc = __builtin_amdgcn_mfma_f32_16x16x32_bf16(aF, bG, acc, 0, 0, 0);
            }
            float p0 = __shfl_xor(acc[0], 1), p1 = __shfl_xor(acc[1], 1);
            float p2 = __shfl_xor(acc[2], 1), p3 = __shfl_xor(acc[3], 1);
            int l15 = lane & 15;
            if (!(l15 & 1)) {
                int kx = nt * 8 + (l15 >> 1);
                if (kx < 20) {
                    int kyi0 = mt * 8 + ((lane >> 4) << 1);
                    fmo[kyi0 * 20 + kx] = make_float2(acc[0] + p1, p0 - acc[1]);
                    fmo[(kyi0 + 1) * 20 + kx] = make_float2(acc[2] + p3, p2 - acc[3]);
                }
            }
        }
    }
}

// ---------------- per-mode 64x64 complex multiply (in-place on fm) -----------------
__global__ __launch_bounds__(256) void specmul_kernel(
    float2* __restrict__ fm,
    const u32* __restrict__ wswk, int nb64)
{
    __shared__ float2 lx[32 * 64];
    __shared__ u32 lw[64 * 64];
    int t = threadIdx.x;
    int mode = blockIdx.x;
    const u32* ws = wswk + (size_t)mode * 4096;
    for (int n = t; n < nb64; n += 256)
        lx[n] = fm[(size_t)n * 800 + mode];
    for (int n = t; n < 4096; n += 256)
        lw[n] = ws[n];
    __syncthreads();
    for (int n = t; n < nb64; n += 256) {
        int b = n >> 6, o = n & 63;
        float re = 0.f, imv = 0.f;
        const float2* xb = lx + b * 64;
#pragma unroll 8
        for (int i = 0; i < 64; ++i) {
            float2 a = xb[i];
            u32 wp = lw[i * 64 + o];
            float wr = __builtin_bit_cast(float, wp << 16);
            float wi = __builtin_bit_cast(float, wp & 0xffff0000u);
            re += a.x * wr - a.y * wi;
            imv += a.x * wi + a.y * wr;
        }
        fm[(size_t)n * 800 + mode] = make_float2(re, imv);
    }
}

// ---------------- invA (MFMA): fm [bc][800] -> g bf16 [b][y][c][48] ----------------
__global__ __launch_bounds__(256) void invA_mfma_kernel(
    const float2* __restrict__ fm, const short* __restrict__ Tiy,
    short* __restrict__ g)
{
    __shared__ short F[48 * 104];
    int t = threadIdx.x;
    int bc = blockIdx.x;
    int lane = t & 63, w = t >> 6;
    int bb = bc >> 6, cc = bc & 63;
    u32* Fw = (u32*)F;
    const float2* src = fm + (size_t)bc * 800;
    for (int i = t; i < 800; i += 256) {
        float2 v = src[i];
        int kyi = i / 20, kx = i - kyi * 20;
        Fw[(2 * kx) * 52 + kyi]     = pack2(v.x, -v.y);
        Fw[(2 * kx + 1) * 52 + kyi] = pack2(v.y, v.x);
    }
    for (int i = t; i < 416; i += 256) Fw[2080 + i] = 0u;
    for (int i = t; i < 384; i += 256) {
        int n = i >> 3, k = i & 7;
        Fw[n * 52 + 40 + k] = 0u;
    }
    __syncthreads();

    short8 aF[3][3];
#pragma unroll
    for (int mt = 0; mt < 3; ++mt)
#pragma unroll
        for (int ks = 0; ks < 3; ++ks)
            aF[mt][ks] = *(const short8*)&F[(mt * 16 + (lane & 15)) * 104 + ks * 32 + (lane >> 4) * 8];

#pragma unroll
    for (int ni = 0; ni < 2; ++ni) {
        int nt = w * 2 + ni;
        int yy = nt * 16 + (lane & 15);
        short8 bF[3];
#pragma unroll
        for (int ks = 0; ks < 3; ++ks)
            bF[ks] = *(const short8*)(Tiy + yy * 96 + ks * 32 + (lane >> 4) * 8);
#pragma unroll
        for (int mt = 0; mt < 3; ++mt) {
            f32x4 acc = (f32x4){0.f, 0.f, 0.f, 0.f};
#pragma unroll
            for (int ks = 0; ks < 3; ++ks)
                acc = __builtin_amdgcn_mfma_f32_16x16x32_bf16(aF[mt][ks], bF[ks], acc, 0, 0, 0);
            int n0 = mt * 16 + (lane >> 4) * 4;
            *(int2*)&g[(((size_t)bb * 128 + yy) * 64 + cc) * 48 + n0] =
                make_int2(pack2(acc[0], acc[1]), pack2(acc[2], acc[3]));
        }
    }
}

// ---------------- fused conv3 + invB + combine: per (b, y-row) ---------------------
// bf16 spine: residual from LDS row 1 (x_old); S1 overlays row 0, C2 overlays row 2.
__global__ __launch_bounds__(256) void convcomb_kernel(
    const short* __restrict__ xb16o,  // [b][y][x][64] bf16 (prev layer)
    const short* __restrict__ wpk,
    const float* __restrict__ cb,
    const short* __restrict__ g,      // [b][y][c][48] bf16
    const short* __restrict__ Winvbg,
    const short* __restrict__ pwk,
    const float* __restrict__ pw,
    const float* __restrict__ pb,
    short* __restrict__ xb16n,
    short* __restrict__ xp)
{
    __shared__ short xlds[3 * 128 * 64];  // rows y-1,y,y+1; post: S1 @row0, C2 @row2
    __shared__ float2 pr[128];
    int t = threadIdx.x;
    int y = blockIdx.x;
    int b = blockIdx.y;
    int lane = t & 63, wid = t >> 6;
    short8 vz = {0, 0, 0, 0, 0, 0, 0, 0};

    // ---- stage conv input rows y-1,y,y+1 from xb16o ----
    const short8* xs = (const short8*)(xb16o + ((size_t)b * 128) * 128 * 64);
#pragma unroll
    for (int i = 0; i < 12; ++i) {
        int c = i * 256 + t;
        int row = c >> 10;
        int rem = c & 1023;
        int xx = rem >> 3, i8 = rem & 7;
        int yy = (y + row + 127) & 127;
        short8 v = xs[((size_t)yy * 128 + xx) * 8 + i8];
        *(short8*)&xlds[(row * 128 + xx) * 64 + ((i8 ^ (xx & 7)) << 3)] = v;
    }
    // ---- conv weights (global) ----
    int o0 = wid * 16;
    const short* wbase = wpk + (size_t)(o0 + (lane & 15)) * 576 + (lane >> 4) * 8;
    short8 aFc[18];
#pragma unroll
    for (int s = 0; s < 18; ++s)
        aFc[s] = *(const short8*)(wbase + s * 32);
    // ---- invB A-frags direct from global g row (k zero-pad beyond 48) ----
    short8 aG0, aG1;
    {
        const short* gb = g + ((size_t)(b * 128 + y)) * 64 * 48
                            + (size_t)(o0 + (lane & 15)) * 48;
        aG0 = *(const short8*)(gb + (lane >> 4) * 8);
        aG1 = ((lane >> 4) < 2) ? *(const short8*)(gb + 32 + (lane >> 4) * 8) : vz;
    }
    // ---- Winvbg B-frags ----
    short8 bFi[8][2];
#pragma unroll
    for (int nf = 0; nf < 8; ++nf)
#pragma unroll
        for (int ks = 0; ks < 2; ++ks) {
            int xx = nf * 16 + (lane & 15);
            bFi[nf][ks] = *(const short8*)(Winvbg + xx * 64 + ks * 32 + (lane >> 4) * 8);
        }

    __syncthreads();

    // ---- conv GEMM: accC[8] in registers ----
    f32x4 accC[8];
#pragma unroll
    for (int f = 0; f < 8; ++f) accC[f] = (f32x4){0.f, 0.f, 0.f, 0.f};
#pragma unroll
    for (int s = 0; s < 18; ++s) {
        const int tap = s >> 1;
        const int ky = tap / 3, kx = tap % 3;
        int ig = (s & 1) * 4 + (lane >> 4);
#pragma unroll
        for (int f = 0; f < 8; ++f) {
            int xx = (f * 16 + (lane & 15) + kx + 127) & 127;
            int off = (ky * 128 + xx) * 64 + ((ig ^ (xx & 7)) << 3);
            short8 bG = *(const short8*)&xlds[off];
            accC[f] = __builtin_amdgcn_mfma_f32_16x16x32_bf16(aFc[s], bG, accC[f], 0, 0, 0);
        }
    }
    // ---- invB GEMM: accI[8] in registers ----
    f32x4 accI[8];
#pragma unroll
    for (int nf = 0; nf < 8; ++nf) {
        f32x4 acc = (f32x4){0.f, 0.f, 0.f, 0.f};
        acc = __builtin_amdgcn_mfma_f32_16x16x32_bf16(aG0, bFi[nf][0], acc, 0, 0, 0);
        acc = __builtin_amdgcn_mfma_f32_16x16x32_bf16(aG1, bFi[nf][1], acc, 0, 0, 0);
        accI[nf] = acc;
    }

    __syncthreads();   // all conv reads done; rows 0 & 2 reusable (row 1 = y kept!)

    // ---- write S1 (xlds row0 @0) + pr, C2 (xlds row2 @16384) = accC + bias ----
    short* S1 = xlds;
    short* C2 = xlds + 16384;
    {
        int cw = o0 + (lane >> 4) * 4;
        int swg = (cw >> 3) & 7;
        int cwo = cw & 7;
        bool dopr = (wid == 0) && ((lane >> 4) == 0);
#pragma unroll
        for (int nf = 0; nf < 8; ++nf) {
            int xx = nf * 16 + (lane & 15);
            int dst = xx * 64 + ((swg ^ (xx & 7)) << 3) + cwo;
            *(int2*)&S1[dst] = make_int2(pack2(accI[nf][0], accI[nf][1]),
                                         pack2(accI[nf][2], accI[nf][3]));
            if (dopr) pr[xx] = make_float2(accI[nf][0] * accI[nf][2],
                                           accI[nf][1] * accI[nf][3]);
        }
        float bias0 = cb[cw], bias1 = cb[cw + 1], bias2 = cb[cw + 2], bias3 = cb[cw + 3];
#pragma unroll
        for (int f = 0; f < 8; ++f) {
            int xx = f * 16 + (lane & 15);
            int dst = xx * 64 + ((swg ^ (xx & 7)) << 3) + cwo;
            *(int2*)&C2[dst] = make_int2(pack2(accC[f][0] + bias0, accC[f][1] + bias1),
                                         pack2(accC[f][2] + bias2, accC[f][3] + bias3));
        }
    }
    // ---- pw B-frags ----
    short8 bFp[4][4];
#pragma unroll
    for (int nf = 0; nf < 4; ++nf)
#pragma unroll
        for (int ks = 0; ks < 4; ++ks) {
            int o = nf * 16 + (lane & 15);
            bFp[nf][ks] = *(const short8*)(pwk + o * 128 + ks * 32 + (lane >> 4) * 8);
        }
    __syncthreads();   // S1/C2/pr visible

    // ---- combine GEMM ----
    f32x4 acc[2][4];
#pragma unroll
    for (int a = 0; a < 2; ++a)
#pragma unroll
        for (int b2 = 0; b2 < 4; ++b2) acc[a][b2] = (f32x4){0.f, 0.f, 0.f, 0.f};

#pragma unroll
    for (int ks = 0; ks < 4; ++ks)
#pragma unroll
        for (int mf = 0; mf < 2; ++mf) {
            int xx = wid * 32 + mf * 16 + (lane & 15);
            int k0 = ks * 32 + (lane >> 4) * 8;
            const short* src = (ks < 2) ? &S1[xx * 64 + ((((k0 >> 3) ^ (xx & 7))) << 3)]
                                        : &C2[xx * 64 + (((((k0 - 64) >> 3) ^ (xx & 7))) << 3)];
            short8 aF = *(const short8*)src;
#pragma unroll
            for (int nf = 0; nf < 4; ++nf)
                acc[mf][nf] = __builtin_amdgcn_mfma_f32_16x16x32_bf16(aF, bFp[nf][ks], acc[mf][nf], 0, 0, 0);
        }

    // ---- epilogue: residual (x_old from LDS row1) + fast tanh -> xb16n + xp ----
#pragma unroll
    for (int mf = 0; mf < 2; ++mf) {
        int xr = wid * 32 + mf * 16 + (lane >> 4) * 4;
        float2 prv0 = pr[xr], prv1 = pr[xr + 1], prv2 = pr[xr + 2], prv3 = pr[xr + 3];
#pragma unroll
        for (int nf = 0; nf < 4; ++nf) {
            int o = nf * 16 + (lane & 15);
            const float* pwrow = pw + o * 130;
            float pw128 = pwrow[128], pw129 = pwrow[129], pbv = pb[o];
            int og = o >> 3, oc = o & 7;
            float xo0 = bf2f(xlds[(128 + xr    ) * 64 + ((og ^ ((xr    ) & 7)) << 3) + oc]);
            float xo1 = bf2f(xlds[(128 + xr + 1) * 64 + ((og ^ ((xr + 1) & 7)) << 3) + oc]);
            float xo2 = bf2f(xlds[(128 + xr + 2) * 64 + ((og ^ ((xr + 2) & 7)) << 3) + oc]);
            float xo3 = bf2f(xlds[(128 + xr + 3) * 64 + ((og ^ ((xr + 3) & 7)) << 3) + oc]);
            float r0 = xo0 + fast_tanh(acc[mf][nf][0] + pbv + pw128 * prv0.x + pw129 * prv0.y);
            float r1 = xo1 + fast_tanh(acc[mf][nf][1] + pbv + pw128 * prv1.x + pw129 * prv1.y);
            float r2 = xo2 + fast_tanh(acc[mf][nf][2] + pbv + pw128 * prv2.x + pw129 * prv2.y);
            float r3 = xo3 + fast_tanh(acc[mf][nf][3] + pbv + pw128 * prv3.x + pw129 * prv3.y);
            size_t hbase = (((size_t)(b * 128 + y)) * 128 + xr) * 64 + o;
            xb16n[hbase]       = (short)f2bf(r0);
            xb16n[hbase + 64]  = (short)f2bf(r1);
            xb16n[hbase + 128] = (short)f2bf(r2);
            xb16n[hbase + 192] = (short)f2bf(r3);
            *(int2*)&xp[((size_t)(b * 64 + o)) * HW + y * 128 + xr] =
                make_int2(pack2(r0, r1), pack2(r2, r3));
        }
    }
}

// ---------------- fc1 (MFMA): xb16 -> gelu MLP -> out ------------------------------
__global__ __launch_bounds__(256) void fc1_mfma_kernel(
    const short* __restrict__ xb16,
    const short* __restrict__ f1wk, const float* __restrict__ b1,
    const float* __restrict__ w2, const float* __restrict__ b2,
    float* __restrict__ out)
{
    __shared__ short X[128 * 72];
    __shared__ float lb1[128], lw2[128];
    int t = threadIdx.x;
    int y = blockIdx.x, b = blockIdx.y;
    int lane = t & 63, w = t >> 6;
    if (t < 128) { lb1[t] = b1[t]; lw2[t] = w2[t]; }
    const short8* src = (const short8*)(xb16 + (((size_t)b * 128 + y) * 128) * 64);
#pragma unroll
    for (int i = 0; i < 4; ++i) {
        int c = i * 256 + t;
        int xx = c >> 3, c8 = c & 7;
        *(short8*)&X[xx * 72 + ((c8 ^ (xx & 7)) << 3)] = src[c];
    }
    __syncthreads();

    float part0 = 0.f, part1 = 0.f;
#pragma unroll
    for (int mt = 0; mt < 8; ++mt) {
        short8 aF[2];
#pragma unroll
        for (int ks = 0; ks < 2; ++ks)
            aF[ks] = *(const short8*)(f1wk + (mt * 16 + (lane & 15)) * 64 + ks * 32 + (lane >> 4) * 8);
#pragma unroll
        for (int ni = 0; ni < 2; ++ni) {
            int xx = (w * 2 + ni) * 16 + (lane & 15);
            f32x4 acc = (f32x4){0.f, 0.f, 0.f, 0.f};
#pragma unroll
            for (int ks = 0; ks < 2; ++ks) {
                int g8 = ks * 4 + (lane >> 4);
                short8 bF = *(const short8*)&X[xx * 72 + ((g8 ^ (xx & 7)) << 3)];
                acc = __builtin_amdgcn_mfma_f32_16x16x32_bf16(aF[ks], bF, acc, 0, 0, 0);
            }
            int m0 = mt * 16 + (lane >> 4) * 4;
            float s = lw2[m0]     * gelu_tanh(acc[0] + lb1[m0])
                    + lw2[m0 + 1] * gelu_tanh(acc[1] + lb1[m0 + 1])
                    + lw2[m0 + 2] * gelu_tanh(acc[2] + lb1[m0 + 2])
                    + lw2[m0 + 3] * gelu_tanh(acc[3] + lb1[m0 + 3]);
            if (ni == 0) part0 += s; else part1 += s;
        }
    }
    part0 += __shfl_xor(part0, 16); part0 += __shfl_xor(part0, 32);
    part1 += __shfl_xor(part1, 16); part1 += __shfl_xor(part1, 32);
    if (lane < 16) {
        float bb = b2[0];
        out[(size_t)b * HW + y * 128 + (w * 2) * 16 + lane] = part0 + bb;
        out[(size_t)b * HW + y * 128 + (w * 2 + 1) * 16 + lane] = part1 + bb;
    }
}

extern "C" void kernel_launch(void* const* d_in, const int* in_sizes, int n_in,
                              void* d_out, int out_size, void* d_ws, size_t ws_size,
                              hipStream_t stream) {
    const float* x      = (const float*)d_in[0];
    const float* qa     = (const float*)d_in[1];
    const float* qb     = (const float*)d_in[2];
    const float* fc0w1  = (const float*)d_in[3];
    const float* fc0b1  = (const float*)d_in[4];
    const float* fc0w2  = (const float*)d_in[5];
    const float* fc0b2  = (const float*)d_in[6];
    const float* sw1r   = (const float*)d_in[7];
    const float* sw1i   = (const float*)d_in[8];
    const float* sw2r   = (const float*)d_in[9];
    const float* sw2i   = (const float*)d_in[10];
    const float* cw     = (const float*)d_in[11];
    const float* cb     = (const float*)d_in[12];
    const float* pw     = (const float*)d_in[13];
    const float* pb     = (const float*)d_in[14];
    const float* fc1w1  = (const float*)d_in[15];
    const float* fc1b1  = (const float*)d_in[16];
    const float* fc1w2  = (const float*)d_in[17];
    const float* fc1b2  = (const float*)d_in[18];

    // const packs (floats)
    const size_t WPK_F = 73728, PWK_F = 16384, WFG_F = 3072, WIB_F = 4096;
    const size_t TFY_F = 5120, TIY_F = 6144, FCK_F = 9216;
    const size_t WSW_F = 13107200;
    const size_t CONST_F = WPK_F + PWK_F + WFG_F + WIB_F + TFY_F + TIY_F + FCK_F + WSW_F;
    // per-batch floats: xb16A 524288 + xb16B 524288 + xp 524288 + g 196608 + fm 102400
    const size_t PER_B_F = 3u * 524288u + 196608u + 102400u;
    int NB = 32;
    while (NB > 1 && ((size_t)NB * PER_B_F + CONST_F) * 4 > ws_size) NB >>= 1;
    if (((size_t)NB * PER_B_F + CONST_F) * 4 > ws_size) return;

    float* fb = (float*)d_ws;
    short* wpk    = (short*)fb;                 fb += WPK_F;
    short* pwk    = (short*)fb;                 fb += PWK_F;
    short* Wfg    = (short*)fb;                 fb += WFG_F;
    short* Winvbg = (short*)fb;                 fb += WIB_F;
    short* Tfy    = (short*)fb;                 fb += TFY_F;
    short* Tiy    = (short*)fb;                 fb += TIY_F;
    short* w1k    = (short*)fb;
    short* w2k    = w1k + 4096;
    short* f1wk   = w1k + 10240;                fb += FCK_F;
    u32*   wswk   = (u32*)fb;                   fb += WSW_F;

    short*  xb16A = (short*)fb;
    short*  xb16B = xb16A + (size_t)NB * 1048576u;
    short*  xp    = xb16B + (size_t)NB * 1048576u;
    short*  g     = xp + (size_t)NB * 1048576u;
    float2* fm    = (float2*)(g + (size_t)NB * 393216u);

    packw_kernel<<<576, 256, 0, stream>>>(cw, wpk);
    packpw_kernel<<<128, 256, 0, stream>>>(pw, pwk);
    packfc_kernel<<<72, 256, 0, stream>>>(fc0w1, fc0w2, fc1w1, w1k, w2k, f1wk);
    gen_dft_kernel<<<144, 256, 0, stream>>>(Wfg, Winvbg, Tfy, Tiy);
    packsw_kernel<<<512, 256, 0, stream>>>(sw1r, sw1i, sw2r, sw2i, wswk);

    for (int b0 = 0; b0 < 32; b0 += NB) {
        front_mfma_kernel<<<dim3(128, NB), 256, 0, stream>>>(
            x + (size_t)b0 * 10 * HW, qa, qb, w1k, fc0b1, w2k, fc0b2, xp, xb16A);

        short* xo = xb16A;
        short* xn = xb16B;
        for (int L = 0; L < 4; ++L) {
            dftfwd_kernel<<<NB * 64, 256, 0, stream>>>(xp, Wfg, Tfy, fm);
            specmul_kernel<<<800, 256, 0, stream>>>(fm, wswk + (size_t)L * 800 * 4096,
                                                    NB * 64);
            invA_mfma_kernel<<<NB * 64, 256, 0, stream>>>(fm, Tiy, g);
            convcomb_kernel<<<dim3(128, NB), 256, 0, stream>>>(
                xo, wpk + (size_t)L * 36864, cb + (size_t)L * 64,
                g, Winvbg, pwk + (size_t)L * 8192, pw + (size_t)L * 8320,
                pb + (size_t)L * 64, xn, xp);
            short* tmp = xo; xo = xn; xn = tmp;
        }

        fc1_mfma_kernel<<<dim3(128, NB), 256, 0, stream>>>(
            xo, f1wk, fc1b1, fc1w2, fc1b2, (float*)d_out + (size_t)b0 * HW);
    }
}

// Round 20
// 1243.336 us; speedup vs baseline: 1.0173x; 1.0043x over previous
//
#include <hip/hip_runtime.h>
#include <math.h>

#define HW 16384   // 128*128

typedef __attribute__((ext_vector_type(8))) short short8;
typedef __attribute__((ext_vector_type(4))) float f32x4;
typedef unsigned int u32;

// fast tanh via v_exp_f32 + v_rcp_f32; saturates cleanly at +-inf
__device__ __forceinline__ float fast_tanh(float x) {
    float e = __expf(-2.0f * x);
    return 2.0f * __builtin_amdgcn_rcpf(1.0f + e) - 1.0f;
}
// gelu_tanh(x) = 0.5x(1+tanh(g)) = x * sigmoid(2g)
__device__ __forceinline__ float gelu_tanh(float x) {
    float x3 = x * x * x;
    float g = 0.7978845608028654f * (x + 0.044715f * x3);
    float e = __expf(-2.0f * g);
    return x * __builtin_amdgcn_rcpf(1.0f + e);
}

__device__ __forceinline__ u32 f2bf(float f) {
    u32 u = __builtin_bit_cast(u32, f);
    return (u + 0x7FFFu + ((u >> 16) & 1u)) >> 16;   // RNE bf16
}
__device__ __forceinline__ u32 pack2(float a, float b) {
    return f2bf(a) | (f2bf(b) << 16);
}
__device__ __forceinline__ float bf2f(short s) {
    return __builtin_bit_cast(float, (u32)(unsigned short)s << 16);
}

// ---------------- const packs ------------------------------------------------------
__global__ __launch_bounds__(256) void packw_kernel(
    const float* __restrict__ cw, short* __restrict__ wpk)
{
    int idx = blockIdx.x * 256 + threadIdx.x;
    if (idx >= 4 * 64 * 576) return;
    int L = idx / 36864, r = idx % 36864;
    int o = r / 576, k = r % 576;
    int tap = k >> 6, i = k & 63;
    wpk[idx] = (short)f2bf(cw[((size_t)(L * 64 + o) * 64 + i) * 9 + tap]);
}
__global__ __launch_bounds__(256) void packpw_kernel(
    const float* __restrict__ pw, short* __restrict__ pwk)
{
    int idx = blockIdx.x * 256 + threadIdx.x;
    if (idx >= 4 * 64 * 128) return;
    int L = idx >> 13, r = idx & 8191;
    int o = r >> 7, k = r & 127;
    pwk[idx] = (short)f2bf(pw[(size_t)L * 8320 + o * 130 + k]);
}
__global__ __launch_bounds__(256) void packfc_kernel(
    const float* __restrict__ fc0w1, const float* __restrict__ fc0w2,
    const float* __restrict__ fc1w1,
    short* __restrict__ w1k, short* __restrict__ w2k, short* __restrict__ f1wk)
{
    int i = blockIdx.x * 256 + threadIdx.x;
    if (i < 4096) {
        int m = i >> 5, k = i & 31;
        w1k[i] = (short)(k < 16 ? f2bf(fc0w1[m * 16 + k]) : 0);
    } else if (i < 10240) {
        int j = i - 4096; int o = j >> 7, m = j & 127;
        w2k[j] = (short)f2bf(fc0w2[o * 128 + m]);
    } else if (i < 18432) {
        int j = i - 10240; int m = j >> 6, c = j & 63;
        f1wk[j] = (short)f2bf(fc1w1[m * 64 + c]);
    }
}
__global__ __launch_bounds__(256) void packsw_kernel(
    const float* __restrict__ sw1r, const float* __restrict__ sw1i,
    const float* __restrict__ sw2r, const float* __restrict__ sw2i,
    u32* __restrict__ wswk)
{
    __shared__ short lr[64][202];
    __shared__ short li[64][202];
    int bi = blockIdx.x;          // 0..511: L = bi>>7, i = (bi>>1)&63, kh = bi&1
    int L = bi >> 7, i = (bi >> 1) & 63, kh = bi & 1;
    int t = threadIdx.x;
    int km0 = kh * 200;
    for (int region = 0; region < 2; ++region) {
        const float* srcR = region ? sw2r : sw1r;
        const float* srcI = region ? sw2i : sw1i;
        size_t sb = ((size_t)(L * 64 + i) * 64) * 400 + km0;
        for (int c = 0; c < 50; ++c) {
            int flat = c * 256 + t;
            int o = flat / 200, km = flat - o * 200;
            lr[o][km] = (short)f2bf(srcR[sb + (size_t)o * 400 + km]);
            li[o][km] = (short)f2bf(srcI[sb + (size_t)o * 400 + km]);
        }
        __syncthreads();
        u32* dst = wswk + ((size_t)L * 800 + (size_t)region * 400 + km0) * 4096 + (size_t)i * 64;
        for (int c = 0; c < 50; ++c) {
            int flat = c * 256 + t;
            int km = flat >> 6, o = flat & 63;
            dst[(size_t)km * 4096 + o] =
                (u32)(unsigned short)lr[o][km] | ((u32)(unsigned short)li[o][km] << 16);
        }
        __syncthreads();
    }
}
__global__ __launch_bounds__(256) void gen_dft_kernel(
    short* __restrict__ Wfg, short* __restrict__ Winvbg,
    short* __restrict__ Tfy, short* __restrict__ Tiy)
{
    int idx = blockIdx.x * 256 + threadIdx.x;
    if (idx < 6144) {
        int n = idx >> 7, xx = idx & 127;
        float val = 0.f;
        if (n < 40) {
            int kx = n >> 1;
            float s, c;
            sincosf(6.283185307179586f * (float)((kx * xx) & 127) / 128.0f, &s, &c);
            val = (n & 1) ? -s : c;
        }
        Wfg[idx] = (short)f2bf(val);
    } else if (idx < 14336) {
        int j = idx - 6144;
        int xx = j >> 6, k = j & 63;
        float val = 0.f;
        if (k < 40) {
            int kx = k >> 1;
            if (kx == 0) {
                val = (k & 1) ? 0.f : (1.0f / 16384.0f);
            } else {
                float s, c;
                sincosf(6.283185307179586f * (float)((kx * xx) & 127) / 128.0f, &s, &c);
                val = ((k & 1) ? -s : c) * (2.0f / 16384.0f);
            }
        }
        Winvbg[j] = (short)f2bf(val);
    } else if (idx < 24576) {
        int j = idx - 14336;      // Tfy [80][128]
        int q = j >> 7, yy = j & 127;
        int kyi = q >> 1;
        int ky = kyi + ((kyi >= 20) ? 88 : 0);
        float s, c;
        sincosf(6.283185307179586f * (float)((ky * yy) & 127) / 128.0f, &s, &c);
        Tfy[j] = (short)f2bf((q & 1) ? s : c);
    } else if (idx < 36864) {
        int j = idx - 24576;      // Tiy [128][96]
        int yy = j / 96, q = j - yy * 96;
        float val = 0.f;
        if (q < 80) {
            int kyi = q >> 1;
            int ky = kyi + ((kyi >= 20) ? 88 : 0);
            float s, c;
            sincosf(6.283185307179586f * (float)((ky * yy) & 127) / 128.0f, &s, &c);
            val = (q & 1) ? s : c;
        }
        Tiy[j] = (short)f2bf(val);
    }
}

// ---------------- front (MFMA): grid+quad+fc0 lift -> xp planar bf16 + xb16 c-last -
__global__ __launch_bounds__(256) void front_mfma_kernel(
    const float* __restrict__ x,
    const float* __restrict__ qa, const float* __restrict__ qb,
    const short* __restrict__ w1k, const float* __restrict__ b1,
    const short* __restrict__ w2k, const float* __restrict__ b2,
    short* __restrict__ xp, short* __restrict__ xb16)
{
    __shared__ short V[128 * 40];
    __shared__ short A2[128 * 136];
    __shared__ float lqa[48], lqb[48], lb1[128], lb2[48];
    int t = threadIdx.x;
    int y = blockIdx.x, b = blockIdx.y;
    int lane = t & 63, w = t >> 6;

    if (t < 48) { lqa[t] = qa[t]; lqb[t] = qb[t]; lb2[t] = b2[t]; }
    if (t >= 128) lb1[t - 128] = b1[t - 128];
    __syncthreads();

    if (t < 128) {
        int xx = t;
        float v[16];
        const float* xsrc = x + (size_t)b * 10 * HW + y * 128 + xx;
#pragma unroll
        for (int c = 0; c < 10; ++c) v[c] = xsrc[c * HW];
        v[10] = (float)y * (1.0f / 127.0f);
        v[11] = (float)xx * (1.0f / 127.0f);
#pragma unroll
        for (int o = 0; o < 4; ++o) {
            float sa = 0.f, sb = 0.f;
#pragma unroll
            for (int c = 0; c < 12; ++c) { sa += lqa[o * 12 + c] * v[c]; sb += lqb[o * 12 + c] * v[c]; }
            v[12 + o] = sa * sb;
        }
        u32* vr = (u32*)&V[xx * 40];
#pragma unroll
        for (int j = 0; j < 8; ++j) vr[j] = pack2(v[2 * j], v[2 * j + 1]);
#pragma unroll
        for (int j = 8; j < 16; ++j) vr[j] = 0u;
        short* op = xp + (size_t)b * 64 * HW + y * 128 + xx;
#pragma unroll
        for (int c = 0; c < 16; ++c) op[(size_t)c * HW] = (short)f2bf(v[c]);
        u32* hb = (u32*)&xb16[(((size_t)b * 128 + y) * 128 + xx) * 64];
#pragma unroll
        for (int j = 0; j < 8; ++j) hb[j] = vr[j];
    }
    __syncthreads();

    // GEMM-a
    {
        short8 aF[2];
#pragma unroll
        for (int mi = 0; mi < 2; ++mi)
            aF[mi] = *(const short8*)(w1k + ((w * 2 + mi) * 16 + (lane & 15)) * 32 + (lane >> 4) * 8);
        f32x4 acc[2][8];
#pragma unroll
        for (int mi = 0; mi < 2; ++mi)
#pragma unroll
            for (int nf = 0; nf < 8; ++nf) acc[mi][nf] = (f32x4){0.f, 0.f, 0.f, 0.f};
#pragma unroll
        for (int nf = 0; nf < 8; ++nf) {
            int xx = nf * 16 + (lane & 15);
            short8 bF = *(const short8*)&V[xx * 40 + (lane >> 4) * 8];
#pragma unroll
            for (int mi = 0; mi < 2; ++mi)
                acc[mi][nf] = __builtin_amdgcn_mfma_f32_16x16x32_bf16(aF[mi], bF, acc[mi][nf], 0, 0, 0);
        }
#pragma unroll
        for (int mi = 0; mi < 2; ++mi) {
            int m0 = (w * 2 + mi) * 16 + (lane >> 4) * 4;
            float bb0 = lb1[m0], bb1 = lb1[m0 + 1], bb2 = lb1[m0 + 2], bb3 = lb1[m0 + 3];
#pragma unroll
            for (int nf = 0; nf < 8; ++nf) {
                int xx = nf * 16 + (lane & 15);
                float h0 = gelu_tanh(acc[mi][nf][0] + bb0);
                float h1 = gelu_tanh(acc[mi][nf][1] + bb1);
                float h2 = gelu_tanh(acc[mi][nf][2] + bb2);
                float h3 = gelu_tanh(acc[mi][nf][3] + bb3);
                *(int2*)&A2[xx * 136 + m0] = make_int2(pack2(h0, h1), pack2(h2, h3));
            }
        }
    }
    __syncthreads();

    // GEMM-b
    {
        short8 aF[3][4];
#pragma unroll
        for (int mt = 0; mt < 3; ++mt)
#pragma unroll
            for (int ks = 0; ks < 4; ++ks)
                aF[mt][ks] = *(const short8*)(w2k + (mt * 16 + (lane & 15)) * 128 + ks * 32 + (lane >> 4) * 8);
#pragma unroll
        for (int ni = 0; ni < 2; ++ni) {
            int nt = w * 2 + ni;
            int xx = nt * 16 + (lane & 15);
            f32x4 acc[3];
#pragma unroll
            for (int mt = 0; mt < 3; ++mt) acc[mt] = (f32x4){0.f, 0.f, 0.f, 0.f};
#pragma unroll
            for (int ks = 0; ks < 4; ++ks) {
                short8 bF = *(const short8*)&A2[xx * 136 + ks * 32 + (lane >> 4) * 8];
#pragma unroll
                for (int mt = 0; mt < 3; ++mt)
                    acc[mt] = __builtin_amdgcn_mfma_f32_16x16x32_bf16(aF[mt][ks], bF, acc[mt], 0, 0, 0);
            }
#pragma unroll
            for (int mt = 0; mt < 3; ++mt) {
                int o0 = mt * 16 + (lane >> 4) * 4;
                float r0 = acc[mt][0] + lb2[o0], r1 = acc[mt][1] + lb2[o0 + 1];
                float r2 = acc[mt][2] + lb2[o0 + 2], r3 = acc[mt][3] + lb2[o0 + 3];
                short* op = xp + (size_t)b * 64 * HW + (size_t)(16 + o0) * HW + y * 128 + xx;
                op[0] = (short)f2bf(r0); op[HW] = (short)f2bf(r1);
                op[2 * HW] = (short)f2bf(r2); op[3 * HW] = (short)f2bf(r3);
                *(int2*)&xb16[(((size_t)b * 128 + y) * 128 + xx) * 64 + 16 + o0] =
                    make_int2(pack2(r0, r1), pack2(r2, r3));
            }
        }
    }
}

// ---------------- fused dft1+dft2 (MFMA): per bc, xp (bf16 planar) -> fm [bc][800] --
__global__ __launch_bounds__(256) void dftfwd_kernel(
    const short* __restrict__ xp, const short* __restrict__ Wfg,
    const short* __restrict__ Tfy, float2* __restrict__ fm)
{
    __shared__ short img[128 * 128];
    __shared__ short S[48 * 140];
    int t = threadIdx.x;
    int bc = blockIdx.x;
    int lane = t & 63, w = t >> 6;

    const short8* src = (const short8*)(xp + (size_t)bc * HW);
#pragma unroll
    for (int i = 0; i < 8; ++i) {
        int chunk = i * 256 + t;
        int y = chunk >> 4, x8 = chunk & 15;
        short8 v = src[y * 16 + x8];
        *(short8*)&img[y * 128 + ((x8 ^ (y & 7)) << 3)] = v;
    }
    for (int z = t; z < 560; z += 256) ((u32*)S)[2800 + z] = 0u;

    short8 bF[3][4];
#pragma unroll
    for (int nf = 0; nf < 3; ++nf)
#pragma unroll
        for (int ks = 0; ks < 4; ++ks) {
            int n = nf * 16 + (lane & 15);
            bF[nf][ks] = *(const short8*)(Wfg + n * 128 + ks * 32 + (lane >> 4) * 8);
        }
    __syncthreads();

    {
        f32x4 acc[2][3];
#pragma unroll
        for (int a = 0; a < 2; ++a)
#pragma unroll
            for (int b2 = 0; b2 < 3; ++b2) acc[a][b2] = (f32x4){0.f, 0.f, 0.f, 0.f};
#pragma unroll
        for (int ks = 0; ks < 4; ++ks)
#pragma unroll
            for (int mf = 0; mf < 2; ++mf) {
                int y = w * 32 + mf * 16 + (lane & 15);
                int x0 = ks * 32 + (lane >> 4) * 8;
                short8 aF = *(const short8*)&img[y * 128 + ((((x0 >> 3) ^ (y & 7))) << 3)];
#pragma unroll
                for (int nf = 0; nf < 3; ++nf)
                    acc[mf][nf] = __builtin_amdgcn_mfma_f32_16x16x32_bf16(aF, bF[nf][ks], acc[mf][nf], 0, 0, 0);
            }
#pragma unroll
        for (int mf = 0; mf < 2; ++mf)
#pragma unroll
            for (int nf = 0; nf < 3; ++nf) {
                int n = nf * 16 + (lane & 15);
                if (n < 40) {
                    int y0 = w * 32 + mf * 16 + (lane >> 4) * 4;
                    *(int2*)&S[n * 140 + y0] = make_int2(pack2(acc[mf][nf][0], acc[mf][nf][1]),
                                                         pack2(acc[mf][nf][2], acc[mf][nf][3]));
                }
            }
    }
    __syncthreads();

    float2* fmo = fm + (size_t)bc * 800;
#pragma unroll
    for (int pi = 0; pi < 4; ++pi) {
        int p = w + pi * 4;
        if (p < 15) {
            int mt = p / 3, nt = p % 3;
            f32x4 acc = (f32x4){0.f, 0.f, 0.f, 0.f};
#pragma unroll
            for (int ks = 0; ks < 4; ++ks) {
                short8 aF = *(const short8*)(Tfy + (mt * 16 + (lane & 15)) * 128 + ks * 32 + (lane >> 4) * 8);
                short8 bG = *(const short8*)&S[(nt * 16 + (lane & 15)) * 140 + ks * 32 + (lane >> 4) * 8];
                acc = __builtin_amdgcn_mfma_f32_16x16x32_bf16(aF, bG, acc, 0, 0, 0);
            }
            float p0 = __shfl_xor(acc[0], 1), p1 = __shfl_xor(acc[1], 1);
            float p2 = __shfl_xor(acc[2], 1), p3 = __shfl_xor(acc[3], 1);
            int l15 = lane & 15;
            if (!(l15 & 1)) {
                int kx = nt * 8 + (l15 >> 1);
                if (kx < 20) {
                    int kyi0 = mt * 8 + ((lane >> 4) << 1);
                    fmo[kyi0 * 20 + kx] = make_float2(acc[0] + p1, p0 - acc[1]);
                    fmo[(kyi0 + 1) * 20 + kx] = make_float2(acc[2] + p3, p2 - acc[3]);
                }
            }
        }
    }
}

// ---------------- per-mode 64x64 complex multiply (in-place on fm) -----------------
__global__ __launch_bounds__(256) void specmul_kernel(
    float2* __restrict__ fm,
    const u32* __restrict__ wswk, int nb64)
{
    __shared__ float2 lx[32 * 64];
    __shared__ u32 lw[64 * 64];
    int t = threadIdx.x;
    int mode = blockIdx.x;
    const u32* ws = wswk + (size_t)mode * 4096;
    for (int n = t; n < nb64; n += 256)
        lx[n] = fm[(size_t)n * 800 + mode];
    for (int n = t; n < 4096; n += 256)
        lw[n] = ws[n];
    __syncthreads();
    for (int n = t; n < nb64; n += 256) {
        int b = n >> 6, o = n & 63;
        float re = 0.f, imv = 0.f;
        const float2* xb = lx + b * 64;
#pragma unroll 8
        for (int i = 0; i < 64; ++i) {
            float2 a = xb[i];
            u32 wp = lw[i * 64 + o];
            float wr = __builtin_bit_cast(float, wp << 16);
            float wi = __builtin_bit_cast(float, wp & 0xffff0000u);
            re += a.x * wr - a.y * wi;
            imv += a.x * wi + a.y * wr;
        }
        fm[(size_t)n * 800 + mode] = make_float2(re, imv);
    }
}

// ---------------- invA (MFMA): fm [bc][800] -> g bf16 [b][y][c][48] ----------------
__global__ __launch_bounds__(256) void invA_mfma_kernel(
    const float2* __restrict__ fm, const short* __restrict__ Tiy,
    short* __restrict__ g)
{
    __shared__ short F[48 * 104];
    int t = threadIdx.x;
    int bc = blockIdx.x;
    int lane = t & 63, w = t >> 6;
    int bb = bc >> 6, cc = bc & 63;
    u32* Fw = (u32*)F;
    const float2* src = fm + (size_t)bc * 800;
    for (int i = t; i < 800; i += 256) {
        float2 v = src[i];
        int kyi = i / 20, kx = i - kyi * 20;
        Fw[(2 * kx) * 52 + kyi]     = pack2(v.x, -v.y);
        Fw[(2 * kx + 1) * 52 + kyi] = pack2(v.y, v.x);
    }
    for (int i = t; i < 416; i += 256) Fw[2080 + i] = 0u;
    for (int i = t; i < 384; i += 256) {
        int n = i >> 3, k = i & 7;
        Fw[n * 52 + 40 + k] = 0u;
    }
    __syncthreads();

    short8 aF[3][3];
#pragma unroll
    for (int mt = 0; mt < 3; ++mt)
#pragma unroll
        for (int ks = 0; ks < 3; ++ks)
            aF[mt][ks] = *(const short8*)&F[(mt * 16 + (lane & 15)) * 104 + ks * 32 + (lane >> 4) * 8];

#pragma unroll
    for (int ni = 0; ni < 2; ++ni) {
        int nt = w * 2 + ni;
        int yy = nt * 16 + (lane & 15);
        short8 bF[3];
#pragma unroll
        for (int ks = 0; ks < 3; ++ks)
            bF[ks] = *(const short8*)(Tiy + yy * 96 + ks * 32 + (lane >> 4) * 8);
#pragma unroll
        for (int mt = 0; mt < 3; ++mt) {
            f32x4 acc = (f32x4){0.f, 0.f, 0.f, 0.f};
#pragma unroll
            for (int ks = 0; ks < 3; ++ks)
                acc = __builtin_amdgcn_mfma_f32_16x16x32_bf16(aF[mt][ks], bF[ks], acc, 0, 0, 0);
            int n0 = mt * 16 + (lane >> 4) * 4;
            *(int2*)&g[(((size_t)bb * 128 + yy) * 64 + cc) * 48 + n0] =
                make_int2(pack2(acc[0], acc[1]), pack2(acc[2], acc[3]));
        }
    }
}

// ---------------- fused conv3 + invB + combine: per (b, y-row) ---------------------
// bf16 spine: residual from LDS row 1 (x_old); S1 overlays row 0, C2 overlays row 2.
__global__ __launch_bounds__(256) void convcomb_kernel(
    const short* __restrict__ xb16o,  // [b][y][x][64] bf16 (prev layer)
    const short* __restrict__ wpk,
    const float* __restrict__ cb,
    const short* __restrict__ g,      // [b][y][c][48] bf16
    const short* __restrict__ Winvbg,
    const short* __restrict__ pwk,
    const float* __restrict__ pw,
    const float* __restrict__ pb,
    short* __restrict__ xb16n,
    short* __restrict__ xp)
{
    __shared__ short xlds[3 * 128 * 64];  // rows y-1,y,y+1; post: S1 @row0, C2 @row2
    __shared__ float2 pr[128];
    int t = threadIdx.x;
    int y = blockIdx.x;
    int b = blockIdx.y;
    int lane = t & 63, wid = t >> 6;
    short8 vz = {0, 0, 0, 0, 0, 0, 0, 0};

    // ---- stage conv input rows y-1,y,y+1 from xb16o ----
    const short8* xs = (const short8*)(xb16o + ((size_t)b * 128) * 128 * 64);
#pragma unroll
    for (int i = 0; i < 12; ++i) {
        int c = i * 256 + t;
        int row = c >> 10;
        int rem = c & 1023;
        int xx = rem >> 3, i8 = rem & 7;
        int yy = (y + row + 127) & 127;
        short8 v = xs[((size_t)yy * 128 + xx) * 8 + i8];
        *(short8*)&xlds[(row * 128 + xx) * 64 + ((i8 ^ (xx & 7)) << 3)] = v;
    }
    // ---- conv weights (global) ----
    int o0 = wid * 16;
    const short* wbase = wpk + (size_t)(o0 + (lane & 15)) * 576 + (lane >> 4) * 8;
    short8 aFc[18];
#pragma unroll
    for (int s = 0; s < 18; ++s)
        aFc[s] = *(const short8*)(wbase + s * 32);
    // ---- invB A-frags direct from global g row (k zero-pad beyond 48) ----
    short8 aG0, aG1;
    {
        const short* gb = g + ((size_t)(b * 128 + y)) * 64 * 48
                            + (size_t)(o0 + (lane & 15)) * 48;
        aG0 = *(const short8*)(gb + (lane >> 4) * 8);
        aG1 = ((lane >> 4) < 2) ? *(const short8*)(gb + 32 + (lane >> 4) * 8) : vz;
    }
    // ---- Winvbg B-frags ----
    short8 bFi[8][2];
#pragma unroll
    for (int nf = 0; nf < 8; ++nf)
#pragma unroll
        for (int ks = 0; ks < 2; ++ks) {
            int xx = nf * 16 + (lane & 15);
            bFi[nf][ks] = *(const short8*)(Winvbg + xx * 64 + ks * 32 + (lane >> 4) * 8);
        }

    __syncthreads();

    // ---- conv GEMM: accC[8] in registers ----
    f32x4 accC[8];
#pragma unroll
    for (int f = 0; f < 8; ++f) accC[f] = (f32x4){0.f, 0.f, 0.f, 0.f};
#pragma unroll
    for (int s = 0; s < 18; ++s) {
        const int tap = s >> 1;
        const int ky = tap / 3, kx = tap % 3;
        int ig = (s & 1) * 4 + (lane >> 4);
#pragma unroll
        for (int f = 0; f < 8; ++f) {
            int xx = (f * 16 + (lane & 15) + kx + 127) & 127;
            int off = (ky * 128 + xx) * 64 + ((ig ^ (xx & 7)) << 3);
            short8 bG = *(const short8*)&xlds[off];
            accC[f] = __builtin_amdgcn_mfma_f32_16x16x32_bf16(aFc[s], bG, accC[f], 0, 0, 0);
        }
    }
    // ---- invB GEMM: accI[8] in registers ----
    f32x4 accI[8];
#pragma unroll
    for (int nf = 0; nf < 8; ++nf) {
        f32x4 acc = (f32x4){0.f, 0.f, 0.f, 0.f};
        acc = __builtin_amdgcn_mfma_f32_16x16x32_bf16(aG0, bFi[nf][0], acc, 0, 0, 0);
        acc = __builtin_amdgcn_mfma_f32_16x16x32_bf16(aG1, bFi[nf][1], acc, 0, 0, 0);
        accI[nf] = acc;
    }

    __syncthreads();   // all conv reads done; rows 0 & 2 reusable (row 1 = y kept!)

    // ---- write S1 (xlds row0 @0) + pr, C2 (xlds row2 @16384) = accC + bias ----
    short* S1 = xlds;
    short* C2 = xlds + 16384;
    {
        int cw = o0 + (lane >> 4) * 4;
        int swg = (cw >> 3) & 7;
        int cwo = cw & 7;
        bool dopr = (wid == 0) && ((lane >> 4) == 0);
#pragma unroll
        for (int nf = 0; nf < 8; ++nf) {
            int xx = nf * 16 + (lane & 15);
            int dst = xx * 64 + ((swg ^ (xx & 7)) << 3) + cwo;
            *(int2*)&S1[dst] = make_int2(pack2(accI[nf][0], accI[nf][1]),
                                         pack2(accI[nf][2], accI[nf][3]));
            if (dopr) pr[xx] = make_float2(accI[nf][0] * accI[nf][2],
                                           accI[nf][1] * accI[nf][3]);
        }
        float bias0 = cb[cw], bias1 = cb[cw + 1], bias2 = cb[cw + 2], bias3 = cb[cw + 3];
#pragma unroll
        for (int f = 0; f < 8; ++f) {
            int xx = f * 16 + (lane & 15);
            int dst = xx * 64 + ((swg ^ (xx & 7)) << 3) + cwo;
            *(int2*)&C2[dst] = make_int2(pack2(accC[f][0] + bias0, accC[f][1] + bias1),
                                         pack2(accC[f][2] + bias2, accC[f][3] + bias3));
        }
    }
    // ---- pw B-frags ----
    short8 bFp[4][4];
#pragma unroll
    for (int nf = 0; nf < 4; ++nf)
#pragma unroll
        for (int ks = 0; ks < 4; ++ks) {
            int o = nf * 16 + (lane & 15);
            bFp[nf][ks] = *(const short8*)(pwk + o * 128 + ks * 32 + (lane >> 4) * 8);
        }
    __syncthreads();   // S1/C2/pr visible

    // ---- combine GEMM ----
    f32x4 acc[2][4];
#pragma unroll
    for (int a = 0; a < 2; ++a)
#pragma unroll
        for (int b2 = 0; b2 < 4; ++b2) acc[a][b2] = (f32x4){0.f, 0.f, 0.f, 0.f};

#pragma unroll
    for (int ks = 0; ks < 4; ++ks)
#pragma unroll
        for (int mf = 0; mf < 2; ++mf) {
            int xx = wid * 32 + mf * 16 + (lane & 15);
            int k0 = ks * 32 + (lane >> 4) * 8;
            const short* src = (ks < 2) ? &S1[xx * 64 + ((((k0 >> 3) ^ (xx & 7))) << 3)]
                                        : &C2[xx * 64 + (((((k0 - 64) >> 3) ^ (xx & 7))) << 3)];
            short8 aF = *(const short8*)src;
#pragma unroll
            for (int nf = 0; nf < 4; ++nf)
                acc[mf][nf] = __builtin_amdgcn_mfma_f32_16x16x32_bf16(aF, bFp[nf][ks], acc[mf][nf], 0, 0, 0);
        }

    // ---- epilogue: residual (x_old from LDS row1) + fast tanh -> xb16n + xp ----
#pragma unroll
    for (int mf = 0; mf < 2; ++mf) {
        int xr = wid * 32 + mf * 16 + (lane >> 4) * 4;
        float2 prv0 = pr[xr], prv1 = pr[xr + 1], prv2 = pr[xr + 2], prv3 = pr[xr + 3];
#pragma unroll
        for (int nf = 0; nf < 4; ++nf) {
            int o = nf * 16 + (lane & 15);
            const float* pwrow = pw + o * 130;
            float pw128 = pwrow[128], pw129 = pwrow[129], pbv = pb[o];
            int og = o >> 3, oc = o & 7;
            float xo0 = bf2f(xlds[(128 + xr    ) * 64 + ((og ^ ((xr    ) & 7)) << 3) + oc]);
            float xo1 = bf2f(xlds[(128 + xr + 1) * 64 + ((og ^ ((xr + 1) & 7)) << 3) + oc]);
            float xo2 = bf2f(xlds[(128 + xr + 2) * 64 + ((og ^ ((xr + 2) & 7)) << 3) + oc]);
            float xo3 = bf2f(xlds[(128 + xr + 3) * 64 + ((og ^ ((xr + 3) & 7)) << 3) + oc]);
            float r0 = xo0 + fast_tanh(acc[mf][nf][0] + pbv + pw128 * prv0.x + pw129 * prv0.y);
            float r1 = xo1 + fast_tanh(acc[mf][nf][1] + pbv + pw128 * prv1.x + pw129 * prv1.y);
            float r2 = xo2 + fast_tanh(acc[mf][nf][2] + pbv + pw128 * prv2.x + pw129 * prv2.y);
            float r3 = xo3 + fast_tanh(acc[mf][nf][3] + pbv + pw128 * prv3.x + pw129 * prv3.y);
            size_t hbase = (((size_t)(b * 128 + y)) * 128 + xr) * 64 + o;
            xb16n[hbase]       = (short)f2bf(r0);
            xb16n[hbase + 64]  = (short)f2bf(r1);
            xb16n[hbase + 128] = (short)f2bf(r2);
            xb16n[hbase + 192] = (short)f2bf(r3);
            *(int2*)&xp[((size_t)(b * 64 + o)) * HW + y * 128 + xr] =
                make_int2(pack2(r0, r1), pack2(r2, r3));
        }
    }
}

// ---------------- fc1 (MFMA): xb16 -> gelu MLP -> out ------------------------------
__global__ __launch_bounds__(256) void fc1_mfma_kernel(
    const short* __restrict__ xb16,
    const short* __restrict__ f1wk, const float* __restrict__ b1,
    const float* __restrict__ w2, const float* __restrict__ b2,
    float* __restrict__ out)
{
    __shared__ short X[128 * 72];
    __shared__ float lb1[128], lw2[128];
    int t = threadIdx.x;
    int y = blockIdx.x, b = blockIdx.y;
    int lane = t & 63, w = t >> 6;
    if (t < 128) { lb1[t] = b1[t]; lw2[t] = w2[t]; }
    const short8* src = (const short8*)(xb16 + (((size_t)b * 128 + y) * 128) * 64);
#pragma unroll
    for (int i = 0; i < 4; ++i) {
        int c = i * 256 + t;
        int xx = c >> 3, c8 = c & 7;
        *(short8*)&X[xx * 72 + ((c8 ^ (xx & 7)) << 3)] = src[c];
    }
    __syncthreads();

    float part0 = 0.f, part1 = 0.f;
#pragma unroll
    for (int mt = 0; mt < 8; ++mt) {
        short8 aF[2];
#pragma unroll
        for (int ks = 0; ks < 2; ++ks)
            aF[ks] = *(const short8*)(f1wk + (mt * 16 + (lane & 15)) * 64 + ks * 32 + (lane >> 4) * 8);
#pragma unroll
        for (int ni = 0; ni < 2; ++ni) {
            int xx = (w * 2 + ni) * 16 + (lane & 15);
            f32x4 acc = (f32x4){0.f, 0.f, 0.f, 0.f};
#pragma unroll
            for (int ks = 0; ks < 2; ++ks) {
                int g8 = ks * 4 + (lane >> 4);
                short8 bF = *(const short8*)&X[xx * 72 + ((g8 ^ (xx & 7)) << 3)];
                acc = __builtin_amdgcn_mfma_f32_16x16x32_bf16(aF[ks], bF, acc, 0, 0, 0);
            }
            int m0 = mt * 16 + (lane >> 4) * 4;
            float s = lw2[m0]     * gelu_tanh(acc[0] + lb1[m0])
                    + lw2[m0 + 1] * gelu_tanh(acc[1] + lb1[m0 + 1])
                    + lw2[m0 + 2] * gelu_tanh(acc[2] + lb1[m0 + 2])
                    + lw2[m0 + 3] * gelu_tanh(acc[3] + lb1[m0 + 3]);
            if (ni == 0) part0 += s; else part1 += s;
        }
    }
    part0 += __shfl_xor(part0, 16); part0 += __shfl_xor(part0, 32);
    part1 += __shfl_xor(part1, 16); part1 += __shfl_xor(part1, 32);
    if (lane < 16) {
        float bb = b2[0];
        out[(size_t)b * HW + y * 128 + (w * 2) * 16 + lane] = part0 + bb;
        out[(size_t)b * HW + y * 128 + (w * 2 + 1) * 16 + lane] = part1 + bb;
    }
}

extern "C" void kernel_launch(void* const* d_in, const int* in_sizes, int n_in,
                              void* d_out, int out_size, void* d_ws, size_t ws_size,
                              hipStream_t stream) {
    const float* x      = (const float*)d_in[0];
    const float* qa     = (const float*)d_in[1];
    const float* qb     = (const float*)d_in[2];
    const float* fc0w1  = (const float*)d_in[3];
    const float* fc0b1  = (const float*)d_in[4];
    const float* fc0w2  = (const float*)d_in[5];
    const float* fc0b2  = (const float*)d_in[6];
    const float* sw1r   = (const float*)d_in[7];
    const float* sw1i   = (const float*)d_in[8];
    const float* sw2r   = (const float*)d_in[9];
    const float* sw2i   = (const float*)d_in[10];
    const float* cw     = (const float*)d_in[11];
    const float* cb     = (const float*)d_in[12];
    const float* pw     = (const float*)d_in[13];
    const float* pb     = (const float*)d_in[14];
    const float* fc1w1  = (const float*)d_in[15];
    const float* fc1b1  = (const float*)d_in[16];
    const float* fc1w2  = (const float*)d_in[17];
    const float* fc1b2  = (const float*)d_in[18];

    // const packs (floats)
    const size_t WPK_F = 73728, PWK_F = 16384, WFG_F = 3072, WIB_F = 4096;
    const size_t TFY_F = 5120, TIY_F = 6144, FCK_F = 9216;
    const size_t WSW_F = 13107200;
    const size_t CONST_F = WPK_F + PWK_F + WFG_F + WIB_F + TFY_F + TIY_F + FCK_F + WSW_F;
    // per-batch floats: xb16A 524288 + xb16B 524288 + xp 524288 + g 196608 + fm 102400
    const size_t PER_B_F = 3u * 524288u + 196608u + 102400u;
    int NB = 32;
    while (NB > 1 && ((size_t)NB * PER_B_F + CONST_F) * 4 > ws_size) NB >>= 1;
    if (((size_t)NB * PER_B_F + CONST_F) * 4 > ws_size) return;

    float* fb = (float*)d_ws;
    short* wpk    = (short*)fb;                 fb += WPK_F;
    short* pwk    = (short*)fb;                 fb += PWK_F;
    short* Wfg    = (short*)fb;                 fb += WFG_F;
    short* Winvbg = (short*)fb;                 fb += WIB_F;
    short* Tfy    = (short*)fb;                 fb += TFY_F;
    short* Tiy    = (short*)fb;                 fb += TIY_F;
    short* w1k    = (short*)fb;
    short* w2k    = w1k + 4096;
    short* f1wk   = w1k + 10240;                fb += FCK_F;
    u32*   wswk   = (u32*)fb;                   fb += WSW_F;

    short*  xb16A = (short*)fb;
    short*  xb16B = xb16A + (size_t)NB * 1048576u;
    short*  xp    = xb16B + (size_t)NB * 1048576u;
    short*  g     = xp + (size_t)NB * 1048576u;
    float2* fm    = (float2*)(g + (size_t)NB * 393216u);

    packw_kernel<<<576, 256, 0, stream>>>(cw, wpk);
    packpw_kernel<<<128, 256, 0, stream>>>(pw, pwk);
    packfc_kernel<<<72, 256, 0, stream>>>(fc0w1, fc0w2, fc1w1, w1k, w2k, f1wk);
    gen_dft_kernel<<<144, 256, 0, stream>>>(Wfg, Winvbg, Tfy, Tiy);
    packsw_kernel<<<512, 256, 0, stream>>>(sw1r, sw1i, sw2r, sw2i, wswk);

    for (int b0 = 0; b0 < 32; b0 += NB) {
        front_mfma_kernel<<<dim3(128, NB), 256, 0, stream>>>(
            x + (size_t)b0 * 10 * HW, qa, qb, w1k, fc0b1, w2k, fc0b2, xp, xb16A);

        short* xo = xb16A;
        short* xn = xb16B;
        for (int L = 0; L < 4; ++L) {
            dftfwd_kernel<<<NB * 64, 256, 0, stream>>>(xp, Wfg, Tfy, fm);
            specmul_kernel<<<800, 256, 0, stream>>>(fm, wswk + (size_t)L * 800 * 4096,
                                                    NB * 64);
            invA_mfma_kernel<<<NB * 64, 256, 0, stream>>>(fm, Tiy, g);
            convcomb_kernel<<<dim3(128, NB), 256, 0, stream>>>(
                xo, wpk + (size_t)L * 36864, cb + (size_t)L * 64,
                g, Winvbg, pwk + (size_t)L * 8192, pw + (size_t)L * 8320,
                pb + (size_t)L * 64, xn, xp);
            short* tmp = xo; xo = xn; xn = tmp;
        }

        fc1_mfma_kernel<<<dim3(128, NB), 256, 0, stream>>>(
            xo, f1wk, fc1b1, fc1w2, fc1b2, (float*)d_out + (size_t)b0 * HW);
    }
}